// Round 10
// baseline (887.917 us; speedup 1.0000x reference)
//
#include <hip/hip_runtime.h>

// ---------------- constants ----------------
#define T_SEQ 2048
#define DMODEL 1024
#define NH 16
#define NKV 4
#define HEAD_DIM 64
#define FFDIM 2816
#define NVOCAB 32000

// flash-attn tile params
#define QBLK 64
#define KBLK 128
#define KSS 72
#define VTS 136
#define PSS 136

using u16 = unsigned short;
typedef __bf16 bf16x8 __attribute__((ext_vector_type(8)));
typedef float f32x4 __attribute__((ext_vector_type(4)));

__device__ __forceinline__ float b2f(u16 u) {
    union { unsigned int i; float f; } v; v.i = ((unsigned int)u) << 16; return v.f;
}
__device__ __forceinline__ u16 f2b(float f) {
    unsigned int u = __builtin_bit_cast(unsigned int, f);
    unsigned int r = (u + 0x7FFFu + ((u >> 16) & 1u)) >> 16;
    return (u16)r;
}
// async global->LDS, 16B per lane; LDS dest = wave-uniform base + lane*16
__device__ __forceinline__ void gload16(const u16* g, u16* l) {
    __builtin_amdgcn_global_load_lds(
        (const __attribute__((address_space(1))) void*)g,
        (__attribute__((address_space(3))) void*)l, 16, 0, 0);
}

// ---------------- embedding gather ----------------
__global__ __launch_bounds__(256) void embed_kernel(const int* __restrict__ toks,
                                                    const float* __restrict__ emb,
                                                    float* __restrict__ x) {
    int idx = blockIdx.x * 256 + threadIdx.x;
    int t = idx >> 10, d = idx & 1023;
    x[idx] = emb[(size_t)toks[t] * DMODEL + d];
}

// ---------------- rmsnorm: f32 in -> bf16 out ----------------
__global__ __launch_bounds__(256) void rmsnorm_kernel(const float* __restrict__ x,
                                                      const float* __restrict__ w,
                                                      u16* __restrict__ out) {
    __shared__ float red[256];
    const int row = blockIdx.x, tid = threadIdx.x;
    const float* xr = x + (size_t)row * DMODEL;
    float vals[4]; float ss = 0.f;
#pragma unroll
    for (int i = 0; i < 4; i++) { float v = xr[tid + 256 * i]; vals[i] = v; ss += v * v; }
    red[tid] = ss; __syncthreads();
    for (int s = 128; s > 0; s >>= 1) { if (tid < s) red[tid] += red[tid + s]; __syncthreads(); }
    float inv = rsqrtf(red[0] * (1.0f / DMODEL) + 1e-5f);
#pragma unroll
    for (int i = 0; i < 4; i++) {
        int c = tid + 256 * i;
        out[(size_t)row * DMODEL + c] = f2b(vals[i] * inv * w[c]);
    }
}

// ---------------- transpose-cast: in[K][N] f32 -> out[N][K] bf16 ----------------
__global__ __launch_bounds__(256) void tcast_kernel(const float* __restrict__ in,
                                                    u16* __restrict__ out, int K, int N) {
    __shared__ float tile[32][33];
    int bx = blockIdx.x * 32;  // N
    int by = blockIdx.y * 32;  // K
    int tx = threadIdx.x & 31, ty = threadIdx.x >> 5;
#pragma unroll
    for (int i = 0; i < 32; i += 8)
        tile[ty + i][tx] = in[(size_t)(by + ty + i) * N + bx + tx];
    __syncthreads();
#pragma unroll
    for (int i = 0; i < 32; i += 8)
        out[(size_t)(bx + ty + i) * K + by + tx] = f2b(tile[tx][ty + i]);
}

// ---------------- strided transpose for V: fqkv[:,1280:1536](bf16) -> vt[256][T] ----------------
__global__ __launch_bounds__(256) void vtcast_kernel(const u16* __restrict__ fqkv,
                                                     u16* __restrict__ vt) {
    __shared__ u16 tile[32][33];
    int bx = blockIdx.x * 32;  // v-dim (0..255)
    int by = blockIdx.y * 32;  // t
    int tx = threadIdx.x & 31, ty = threadIdx.x >> 5;
#pragma unroll
    for (int i = 0; i < 32; i += 8)
        tile[ty + i][tx] = fqkv[(size_t)(by + ty + i) * 1536 + 1280 + bx + tx];
    __syncthreads();
#pragma unroll
    for (int i = 0; i < 32; i += 8)
        vt[(size_t)(bx + ty + i) * T_SEQ + by + tx] = tile[tx][ty + i];
}

// ---------------- GEMM-BT: C[M,N] = A[M,K](bf16) * BT[N,K](bf16) ----------------
// Tile 128x128, BK=32, 4 waves (2x2). 3-buffer 2-deep pipeline: global_load_lds
// into linear [128][32] LDS; counted s_waitcnt vmcnt(4) + raw s_barrier so the
// next-next tile's loads stay in flight across the barrier (T4). 4 loads/tile:
// outstanding at barrier = {t+1,t+2}=8 -> vmcnt(4) waits exactly tile t+1.
// lgkmcnt(0) before barrier: ds_reads of buf[cur] complete before any wave's
// later gloads overwrite it (overwrite happens 1 barrier later, (t+3)%3==t%3).
// XCD-chunked bijective swizzle: M-tiles sharing a BT panel land on one XCD L2.
// OUT_BF16: bf16 C. ADD: C = R + acc (fused residual), R==C allowed.
template<bool OUT_BF16, bool ADD>
__global__ __launch_bounds__(256) void gemm_bt_kernel(const u16* __restrict__ A,
                                                      const u16* __restrict__ BT,
                                                      void* __restrict__ Cp,
                                                      int N, int K) {
    __shared__ __align__(16) u16 As[3][128 * 32];
    __shared__ __align__(16) u16 Bs[3][128 * 32];
    const int tid = threadIdx.x;
    // XCD-chunked swizzle (m204 bijective form)
    const int gx = gridDim.x;
    const int nwg = gx * gridDim.y;
    const int hwid = blockIdx.y * gx + blockIdx.x;
    const int q = nwg >> 3, r = nwg & 7;
    const int xcd = hwid & 7, rem = hwid >> 3;
    const int wgid = (xcd < r ? xcd * (q + 1) : r * (q + 1) + (xcd - r) * q) + rem;
    const int brow = wgid % gx, bcol = wgid / gx;

    const int w = tid >> 6, lane = tid & 63;
    const int wr = w >> 1, wc = w & 1;
    const int lg = lane >> 4, lr = lane & 15;

    f32x4 acc[4][4] = {};

    // staging: wave w stages rows [32w,32w+32); lane->row w*32+(lane>>2), col8=(lane&3)*8
    const int srow = w * 32 + (lane >> 2);
    const int scol = (lane & 3) << 3;
    const u16* gA = A + (size_t)(brow * 128 + srow) * K + scol;
    const u16* gB = BT + (size_t)(bcol * 128 + srow) * K + scol;
    const size_t koff16 = (size_t)16 * K;
    const int lofs0 = (w * 32) * 32;
    const int lofs1 = (w * 32 + 16) * 32;

    const int nt = K >> 5;
    auto STAGE = [&](int t, int buf) {
        const int kb = t << 5;
        gload16(gA + kb, &As[buf][lofs0]);
        gload16(gA + koff16 + kb, &As[buf][lofs1]);
        gload16(gB + kb, &Bs[buf][lofs0]);
        gload16(gB + koff16 + kb, &Bs[buf][lofs1]);
    };

    // prologue: tiles 0,1 in flight; wait tile 0 (4 newest may remain)
    STAGE(0, 0);
    STAGE(1, 1);
    asm volatile("s_waitcnt vmcnt(4)" ::: "memory");
    __builtin_amdgcn_s_barrier();
    __builtin_amdgcn_sched_barrier(0);

    int cur = 0;
    for (int t = 0; t < nt; t++) {
        if (t + 2 < nt) {
            int nb = cur + 2; if (nb >= 3) nb -= 3;
            STAGE(t + 2, nb);
        }
        bf16x8 aF[4], bF[4];
#pragma unroll
        for (int m = 0; m < 4; m++)
            aF[m] = *(const bf16x8*)(&As[cur][(wr * 64 + m * 16 + lr) * 32 + lg * 8]);
#pragma unroll
        for (int n = 0; n < 4; n++)
            bF[n] = *(const bf16x8*)(&Bs[cur][(wc * 64 + n * 16 + lr) * 32 + lg * 8]);
#pragma unroll
        for (int m = 0; m < 4; m++)
#pragma unroll
            for (int n = 0; n < 4; n++)
                acc[m][n] = __builtin_amdgcn_mfma_f32_16x16x32_bf16(aF[m], bF[n], acc[m][n], 0, 0, 0);
        if (t + 2 < nt) asm volatile("s_waitcnt vmcnt(4) lgkmcnt(0)" ::: "memory");
        else            asm volatile("s_waitcnt vmcnt(0) lgkmcnt(0)" ::: "memory");
        __builtin_amdgcn_s_barrier();
        __builtin_amdgcn_sched_barrier(0);
        cur = (cur == 2) ? 0 : cur + 1;
    }

#pragma unroll
    for (int m = 0; m < 4; m++)
#pragma unroll
        for (int n = 0; n < 4; n++)
#pragma unroll
            for (int j = 0; j < 4; j++) {
                int row = brow * 128 + wr * 64 + m * 16 + lg * 4 + j;
                int col = bcol * 128 + wc * 64 + n * 16 + lr;
                size_t idx = (size_t)row * N + col;
                float v = acc[m][n][j];
                if constexpr (OUT_BF16) {
                    ((u16*)Cp)[idx] = f2b(v);
                } else if constexpr (ADD) {
                    ((float*)Cp)[idx] = ((const float*)Cp)[idx] + v;
                } else {
                    ((float*)Cp)[idx] = v;
                }
            }
}

// ---------------- fallback GEMM (f32 B, non-transposed) — LM head only ----------------
__device__ __forceinline__ int bs_off(int c, int k) {
    return c * 40 + ((((k >> 3) ^ ((c >> 3) & 3)) << 3) | (k & 7));
}

__global__ __launch_bounds__(256) void gemm_f32b_kernel(const u16* __restrict__ A,
                                                        const float* __restrict__ B,
                                                        float* __restrict__ C,
                                                        int N, int K) {
    __shared__ __align__(16) u16 As[128 * 40];
    __shared__ __align__(16) u16 Bs[128 * 40];
    const int tid = threadIdx.x;
    const int brow = blockIdx.y, bcol = blockIdx.x;
    const int wid = tid >> 6, lane = tid & 63;
    const int wr = wid >> 1, wc = wid & 1;
    const int lg = lane >> 4, lr = lane & 15;

    f32x4 acc[4][4] = {};
    const int ar = tid >> 2, ac = (tid & 3) << 3;
    const int bk = tid >> 4, bc = (tid & 15) << 3;

    for (int kb = 0; kb < K; kb += 32) {
        {
            const u16* ga = A + (size_t)(brow * 128 + ar) * K + kb + ac;
            *(uint4*)(&As[ar * 40 + ac]) = *(const uint4*)ga;
            *(uint4*)(&As[(ar + 64) * 40 + ac]) = *(const uint4*)(ga + (size_t)64 * K);
        }
        {
            const float* gb = B + (size_t)(kb + bk) * N + bcol * 128 + bc;
            float4 a0 = *(const float4*)gb;
            float4 a1 = *(const float4*)(gb + 4);
            float4 b0 = *(const float4*)(gb + (size_t)16 * N);
            float4 b1 = *(const float4*)(gb + (size_t)16 * N + 4);
            float f0[8] = {a0.x, a0.y, a0.z, a0.w, a1.x, a1.y, a1.z, a1.w};
            float f1[8] = {b0.x, b0.y, b0.z, b0.w, b1.x, b1.y, b1.z, b1.w};
#pragma unroll
            for (int i = 0; i < 8; i++) {
                Bs[bs_off(bc + i, bk)] = f2b(f0[i]);
                Bs[bs_off(bc + i, bk + 16)] = f2b(f1[i]);
            }
        }
        __syncthreads();

        bf16x8 aF[4], bF[4];
#pragma unroll
        for (int m = 0; m < 4; m++)
            aF[m] = *(const bf16x8*)(&As[(wr * 64 + m * 16 + lr) * 40 + lg * 8]);
#pragma unroll
        for (int n = 0; n < 4; n++) {
            int c = wc * 64 + n * 16 + lr;
            bF[n] = *(const bf16x8*)(&Bs[c * 40 + ((lg ^ ((c >> 3) & 3)) << 3)]);
        }
#pragma unroll
        for (int m = 0; m < 4; m++)
#pragma unroll
            for (int n = 0; n < 4; n++)
                acc[m][n] = __builtin_amdgcn_mfma_f32_16x16x32_bf16(aF[m], bF[n], acc[m][n], 0, 0, 0);
        __syncthreads();
    }

#pragma unroll
    for (int m = 0; m < 4; m++)
#pragma unroll
        for (int n = 0; n < 4; n++)
#pragma unroll
            for (int j = 0; j < 4; j++) {
                int row = brow * 128 + wr * 64 + m * 16 + lg * 4 + j;
                int col = bcol * 128 + wc * 64 + n * 16 + lr;
                C[(size_t)row * N + col] = acc[m][n][j];
            }
}

// ---------------- RoPE: bf16 strided in -> bf16 packed out ----------------
__global__ __launch_bounds__(256) void rope_kernel(const u16* __restrict__ in,
                                                   u16* __restrict__ out, int heads,
                                                   int instride, int incoloff) {
    int idx = blockIdx.x * 256 + threadIdx.x;
    int total = T_SEQ * heads * 32;
    if (idx >= total) return;
    int i = idx & 31;
    int rest = idx >> 5;       // t*heads + h
    int t = rest / heads, hh = rest - t * heads;
    float inv = expf(-(float)i * (9.210340371976184f / 32.0f));
    float ang = (float)t * inv;
    float c = cosf(ang), s = sinf(ang);
    size_t src = (size_t)t * instride + incoloff + hh * HEAD_DIM + 2 * i;
    size_t dst = (size_t)rest * HEAD_DIM + 2 * i;
    float x0 = b2f(in[src]), x1 = b2f(in[src + 1]);
    out[dst]     = f2b(x0 * c - x1 * s);
    out[dst + 1] = f2b(x0 * s + x1 * c);
}

// ---------------- flash attention ----------------
__global__ __launch_bounds__(256) void fattn_kernel(const u16* __restrict__ q,
                                                    const u16* __restrict__ k,
                                                    const u16* __restrict__ vt,
                                                    u16* __restrict__ out) {
    __shared__ __align__(16) u16 Ks[KBLK * KSS];
    __shared__ __align__(16) u16 Vt[HEAD_DIM * VTS];
    __shared__ __align__(16) u16 Ps[QBLK * PSS];
    const int tid = threadIdx.x;
    const int qb0 = blockIdx.x * QBLK, h = blockIdx.y, kvh = h >> 2;
    const int w = tid >> 6, lane = tid & 63;
    const int lg = lane >> 4, lr = lane & 15;

    bf16x8 qf0, qf1;
    {
        const u16* src = q + ((size_t)(qb0 + w * 16 + lr) * NH + h) * HEAD_DIM;
        qf0 = *(const bf16x8*)(src + lg * 8);
        qf1 = *(const bf16x8*)(src + 32 + lg * 8);
    }

    f32x4 acc_o[4] = {};
    float m_run[4] = {-1e30f, -1e30f, -1e30f, -1e30f};
    float l_run[4] = {0.f, 0.f, 0.f, 0.f};

    const int ntiles = (qb0 + QBLK - 1) / KBLK + 1;

    for (int kt = 0; kt < ntiles; kt++) {
        const int kb = kt * KBLK;
        __syncthreads();
        for (int c = tid; c < KBLK * 8; c += 256) {
            int row = c >> 3, c8 = (c & 7) << 3;
            *(uint4*)(&Ks[row * KSS + c8]) =
                *(const uint4*)(k + ((size_t)(kb + row) * NKV + kvh) * HEAD_DIM + c8);
        }
        for (int c = tid; c < HEAD_DIM * 16; c += 256) {
            int d = c >> 4, c16 = (c & 15) << 3;
            *(uint4*)(&Vt[d * VTS + c16]) =
                *(const uint4*)(vt + (size_t)(kvh * HEAD_DIM + d) * T_SEQ + kb + c16);
        }
        __syncthreads();

        f32x4 s[8] = {};
#pragma unroll
        for (int n = 0; n < 8; n++) {
            bf16x8 kf0 = *(const bf16x8*)(&Ks[(n * 16 + lr) * KSS + lg * 8]);
            bf16x8 kf1 = *(const bf16x8*)(&Ks[(n * 16 + lr) * KSS + 32 + lg * 8]);
            s[n] = __builtin_amdgcn_mfma_f32_16x16x32_bf16(qf0, kf0, s[n], 0, 0, 0);
            s[n] = __builtin_amdgcn_mfma_f32_16x16x32_bf16(qf1, kf1, s[n], 0, 0, 0);
        }

#pragma unroll
        for (int j = 0; j < 4; j++) {
            int q_g = qb0 + w * 16 + lg * 4 + j;
            float sv[8];
            float tmax = -1e30f;
#pragma unroll
            for (int n = 0; n < 8; n++) {
                float xx = s[n][j] * 0.125f;
                if (kb + n * 16 + lr > q_g) xx = -1e30f;
                sv[n] = xx;
                tmax = fmaxf(tmax, xx);
            }
#pragma unroll
            for (int mm = 1; mm < 16; mm <<= 1) tmax = fmaxf(tmax, __shfl_xor(tmax, mm));
            float mn = fmaxf(m_run[j], tmax);
            float sc = __expf(m_run[j] - mn);
            m_run[j] = mn;
            float rsum = 0.f;
#pragma unroll
            for (int n = 0; n < 8; n++) {
                float p = __expf(sv[n] - mn);
                rsum += p;
                Ps[(w * 16 + lg * 4 + j) * PSS + n * 16 + lr] = f2b(p);
            }
#pragma unroll
            for (int mm = 1; mm < 16; mm <<= 1) rsum += __shfl_xor(rsum, mm);
            l_run[j] = l_run[j] * sc + rsum;
#pragma unroll
            for (int n = 0; n < 4; n++) acc_o[n][j] *= sc;
        }

#pragma unroll
        for (int ks = 0; ks < 4; ks++) {
            bf16x8 pf = *(const bf16x8*)(&Ps[(w * 16 + lr) * PSS + ks * 32 + lg * 8]);
#pragma unroll
            for (int n = 0; n < 4; n++) {
                bf16x8 vf = *(const bf16x8*)(&Vt[(n * 16 + lr) * VTS + ks * 32 + lg * 8]);
                acc_o[n] = __builtin_amdgcn_mfma_f32_16x16x32_bf16(pf, vf, acc_o[n], 0, 0, 0);
            }
        }
    }

#pragma unroll
    for (int n = 0; n < 4; n++)
#pragma unroll
        for (int j = 0; j < 4; j++) {
            int t = qb0 + w * 16 + lg * 4 + j;
            int d = n * 16 + lr;
            out[((size_t)t * NH + h) * HEAD_DIM + d] = f2b(acc_o[n][j] / l_run[j]);
        }
}

// ---------------- silu(gate)*up from packed bf16 gu[t][5632] -> bf16 [t][2816] ----------------
__global__ __launch_bounds__(256) void silu_mul_kernel(const u16* __restrict__ gu,
                                                       u16* __restrict__ out) {
    int t = blockIdx.x;
    int c = blockIdx.y * 256 + threadIdx.x;   // < 2816
    float gv = b2f(gu[(size_t)t * 5632 + c]);
    float uv = b2f(gu[(size_t)t * 5632 + 2816 + c]);
    float s = gv / (1.f + __expf(-gv));
    out[(size_t)t * FFDIM + c] = f2b(s * uv);
}

// ---------------- host launch ----------------
extern "C" void kernel_launch(void* const* d_in, const int* in_sizes, int n_in,
                              void* d_out, int out_size, void* d_ws, size_t ws_size,
                              hipStream_t stream) {
    const int*   toks = (const int*)d_in[0];
    const float* emb  = (const float*)d_in[1];
    const float* Wq   = (const float*)d_in[2];
    const float* Wk   = (const float*)d_in[3];
    const float* Wv   = (const float*)d_in[4];
    const float* Wo   = (const float*)d_in[5];
    const float* Wg   = (const float*)d_in[6];
    const float* Wu   = (const float*)d_in[7];
    const float* Wd   = (const float*)d_in[8];
    const float* ln1  = (const float*)d_in[9];
    const float* ln2  = (const float*)d_in[10];
    const float* nw   = (const float*)d_in[11];
    const float* Wlm  = (const float*)d_in[12];

    // ---- scratch layout in d_out (262MB, all dead before LM head writes) ----
    char* ob = (char*)d_out;
    const size_t MB = 1024 * 1024;
    float* x    = (float*)(ob + 0 * MB);    // 8MB   residual [T,D] f32
    u16* fqkv   = (u16*)  (ob + 8 * MB);    // 6MB   [T,1536] qkv packed bf16
    u16* fGU    = (u16*)  (ob + 16 * MB);   // 22MB  [T,5632] gate|up packed bf16
    u16* vt     = (u16*)  (ob + 40 * MB);   // 1MB   V^T [256][T]
    u16* qb     = (u16*)  (ob + 42 * MB);   // 4MB
    u16* kb     = (u16*)  (ob + 47 * MB);   // 1MB
    u16* attnb  = (u16*)  (ob + 48 * MB);   // 4MB
    u16* ffb    = (u16*)  (ob + 52 * MB);   // 11.5MB
    size_t woff = 64 * MB;                  // packed bf16 transposed weights (43MB)
    auto walloc = [&](size_t elems) {
        u16* p = (u16*)(ob + woff);
        woff += ((elems * 2 + 255) & ~(size_t)255);
        return p;
    };
    u16 *WqkvT[2], *WoT[2], *WguT[2], *WdT[2];
    for (int l = 0; l < 2; l++) {
        WqkvT[l] = walloc((size_t)1536 * DMODEL);
        WoT[l]   = walloc((size_t)DMODEL * DMODEL);
        WguT[l]  = walloc((size_t)5632 * DMODEL);
        WdT[l]   = walloc((size_t)DMODEL * FFDIM);
    }
    u16* h = (u16*)d_ws;   // 4MB bf16 [T,D]
    bool ws_big = ws_size >= 72 * MB;
    u16* WlmT = ws_big ? (u16*)((char*)d_ws + 4 * MB) : nullptr;  // [NVOCAB][DMODEL]
    (void)in_sizes; (void)n_in; (void)out_size;

    dim3 blk(256);
    auto tcast = [&](const float* in, u16* out, int K, int N) {
        tcast_kernel<<<dim3(N / 32, K / 32), blk, 0, stream>>>(in, out, K, N);
    };
    auto gemm_f32 = [&](const u16* A, const u16* BT, float* C, int N, int K, bool add) {
        dim3 g(T_SEQ / 128, N / 128);
        if (add) gemm_bt_kernel<false, true><<<g, blk, 0, stream>>>(A, BT, (void*)C, N, K);
        else     gemm_bt_kernel<false, false><<<g, blk, 0, stream>>>(A, BT, (void*)C, N, K);
    };
    auto gemm_b16 = [&](const u16* A, const u16* BT, u16* C, int N, int K) {
        dim3 g(T_SEQ / 128, N / 128);
        gemm_bt_kernel<true, false><<<g, blk, 0, stream>>>(A, BT, (void*)C, N, K);
    };

    // ---- one-time weight transpose-casts (packed) ----
    for (int l = 0; l < 2; l++) {
        tcast(Wq + (size_t)l * DMODEL * NH * HEAD_DIM,  WqkvT[l],                         DMODEL, NH * HEAD_DIM);
        tcast(Wk + (size_t)l * DMODEL * NKV * HEAD_DIM, WqkvT[l] + (size_t)1024 * DMODEL, DMODEL, NKV * HEAD_DIM);
        tcast(Wv + (size_t)l * DMODEL * NKV * HEAD_DIM, WqkvT[l] + (size_t)1280 * DMODEL, DMODEL, NKV * HEAD_DIM);
        tcast(Wo + (size_t)l * DMODEL * DMODEL,         WoT[l],  DMODEL, DMODEL);
        tcast(Wg + (size_t)l * DMODEL * FFDIM,          WguT[l],                          DMODEL, FFDIM);
        tcast(Wu + (size_t)l * DMODEL * FFDIM,          WguT[l] + (size_t)FFDIM * DMODEL, DMODEL, FFDIM);
        tcast(Wd + (size_t)l * FFDIM * DMODEL,          WdT[l],  FFDIM, DMODEL);
    }
    if (WlmT) tcast(Wlm, WlmT, DMODEL, NVOCAB);

    embed_kernel<<<dim3(T_SEQ * DMODEL / 256), blk, 0, stream>>>(toks, emb, x);

    for (int l = 0; l < 2; l++) {
        // attn block
        rmsnorm_kernel<<<dim3(T_SEQ), blk, 0, stream>>>(x, ln1 + (size_t)l * DMODEL, h);
        gemm_b16(h, WqkvT[l], fqkv, 1536, DMODEL);
        rope_kernel<<<dim3(T_SEQ * NH * 32 / 256), blk, 0, stream>>>(fqkv, qb, NH, 1536, 0);
        rope_kernel<<<dim3(T_SEQ * NKV * 32 / 256), blk, 0, stream>>>(fqkv, kb, NKV, 1536, 1024);
        vtcast_kernel<<<dim3(8, T_SEQ / 32), blk, 0, stream>>>(fqkv, vt);
        fattn_kernel<<<dim3(T_SEQ / QBLK, NH), blk, 0, stream>>>(qb, kb, vt, attnb);
        gemm_f32(attnb, WoT[l], x, DMODEL, DMODEL, true);   // fused residual add

        // ffn block
        rmsnorm_kernel<<<dim3(T_SEQ), blk, 0, stream>>>(x, ln2 + (size_t)l * DMODEL, h);
        gemm_b16(h, WguT[l], fGU, 5632, DMODEL);
        silu_mul_kernel<<<dim3(T_SEQ, FFDIM / 256), blk, 0, stream>>>(fGU, ffb);
        gemm_f32(ffb, WdT[l], x, DMODEL, FFDIM, true);      // fused residual add
    }

    // final norm + lm head
    rmsnorm_kernel<<<dim3(T_SEQ), blk, 0, stream>>>(x, nw, h);
    if (WlmT) {
        gemm_f32(h, WlmT, (float*)d_out, NVOCAB, DMODEL, false);
    } else {
        dim3 g(NVOCAB / 128, T_SEQ / 128);
        gemm_f32b_kernel<<<g, blk, 0, stream>>>(h, Wlm, (float*)d_out, NVOCAB, DMODEL);
    }
}

// Round 11
// 857.329 us; speedup vs baseline: 1.0357x; 1.0357x over previous
//
#include <hip/hip_runtime.h>

// ---------------- constants ----------------
#define T_SEQ 2048
#define DMODEL 1024
#define NH 16
#define NKV 4
#define HEAD_DIM 64
#define FFDIM 2816
#define NVOCAB 32000

// flash-attn tile params
#define QBLK 64
#define KBLK 128
#define KSS 72
#define VTS 136
#define PSS 136

using u16 = unsigned short;
typedef __bf16 bf16x8 __attribute__((ext_vector_type(8)));
typedef float f32x4 __attribute__((ext_vector_type(4)));

__device__ __forceinline__ float b2f(u16 u) {
    union { unsigned int i; float f; } v; v.i = ((unsigned int)u) << 16; return v.f;
}
__device__ __forceinline__ u16 f2b(float f) {
    unsigned int u = __builtin_bit_cast(unsigned int, f);
    unsigned int r = (u + 0x7FFFu + ((u >> 16) & 1u)) >> 16;
    return (u16)r;
}
// async global->LDS, 16B per lane; LDS dest = wave-uniform base + lane*16
__device__ __forceinline__ void gload16(const u16* g, u16* l) {
    __builtin_amdgcn_global_load_lds(
        (const __attribute__((address_space(1))) void*)g,
        (__attribute__((address_space(3))) void*)l, 16, 0, 0);
}

// ---------------- embedding gather ----------------
__global__ __launch_bounds__(256) void embed_kernel(const int* __restrict__ toks,
                                                    const float* __restrict__ emb,
                                                    float* __restrict__ x) {
    int idx = blockIdx.x * 256 + threadIdx.x;
    int t = idx >> 10, d = idx & 1023;
    x[idx] = emb[(size_t)toks[t] * DMODEL + d];
}

// ---------------- rmsnorm: f32 in -> bf16 out ----------------
__global__ __launch_bounds__(256) void rmsnorm_kernel(const float* __restrict__ x,
                                                      const float* __restrict__ w,
                                                      u16* __restrict__ out) {
    __shared__ float red[256];
    const int row = blockIdx.x, tid = threadIdx.x;
    const float* xr = x + (size_t)row * DMODEL;
    float vals[4]; float ss = 0.f;
#pragma unroll
    for (int i = 0; i < 4; i++) { float v = xr[tid + 256 * i]; vals[i] = v; ss += v * v; }
    red[tid] = ss; __syncthreads();
    for (int s = 128; s > 0; s >>= 1) { if (tid < s) red[tid] += red[tid + s]; __syncthreads(); }
    float inv = rsqrtf(red[0] * (1.0f / DMODEL) + 1e-5f);
#pragma unroll
    for (int i = 0; i < 4; i++) {
        int c = tid + 256 * i;
        out[(size_t)row * DMODEL + c] = f2b(vals[i] * inv * w[c]);
    }
}

// ---------------- transpose-cast: in[K][N] f32 -> out[N][K] bf16 ----------------
__global__ __launch_bounds__(256) void tcast_kernel(const float* __restrict__ in,
                                                    u16* __restrict__ out, int K, int N) {
    __shared__ float tile[32][33];
    int bx = blockIdx.x * 32;  // N
    int by = blockIdx.y * 32;  // K
    int tx = threadIdx.x & 31, ty = threadIdx.x >> 5;
#pragma unroll
    for (int i = 0; i < 32; i += 8)
        tile[ty + i][tx] = in[(size_t)(by + ty + i) * N + bx + tx];
    __syncthreads();
#pragma unroll
    for (int i = 0; i < 32; i += 8)
        out[(size_t)(bx + ty + i) * K + by + tx] = f2b(tile[tx][ty + i]);
}

// ---------------- strided transpose for V: fqkv[:,1280:1536](bf16) -> vt[256][T] ----------------
__global__ __launch_bounds__(256) void vtcast_kernel(const u16* __restrict__ fqkv,
                                                     u16* __restrict__ vt) {
    __shared__ u16 tile[32][33];
    int bx = blockIdx.x * 32;  // v-dim (0..255)
    int by = blockIdx.y * 32;  // t
    int tx = threadIdx.x & 31, ty = threadIdx.x >> 5;
#pragma unroll
    for (int i = 0; i < 32; i += 8)
        tile[ty + i][tx] = fqkv[(size_t)(by + ty + i) * 1536 + 1280 + bx + tx];
    __syncthreads();
#pragma unroll
    for (int i = 0; i < 32; i += 8)
        vt[(size_t)(bx + ty + i) * T_SEQ + by + tx] = tile[tx][ty + i];
}

// ---------------- GEMM-BT: C[M,N] = A[M,K](bf16) * BT[N,K](bf16) ----------------
// Tile 128x128, BK=32, 4 waves (2x2). Double-buffered m97-style staging:
// global_load_lds(16B) into linear [128][32] LDS; stage(t+1) issued BEFORE
// compute(t); one __syncthreads per K-step (implicit vmcnt(0)+lgkmcnt(0)).
// 32KB LDS -> 5 blocks/CU; inter-block TLP covers the barrier drain (round-10
// lesson: deeper per-block pipeline at lower occupancy is a net LOSS).
// XCD-chunked bijective swizzle: M-tiles sharing a BT panel land on one XCD L2.
// OUT_BF16: bf16 C. ADD: C = C + acc (fused residual), in-place safe.
template<bool OUT_BF16, bool ADD>
__global__ __launch_bounds__(256) void gemm_bt_kernel(const u16* __restrict__ A,
                                                      const u16* __restrict__ BT,
                                                      void* __restrict__ Cp,
                                                      int N, int K) {
    __shared__ __align__(16) u16 As[2][128 * 32];
    __shared__ __align__(16) u16 Bs[2][128 * 32];
    const int tid = threadIdx.x;
    // XCD-chunked swizzle (m204 bijective form)
    const int gx = gridDim.x;
    const int nwg = gx * gridDim.y;
    const int hwid = blockIdx.y * gx + blockIdx.x;
    const int q = nwg >> 3, r = nwg & 7;
    const int xcd = hwid & 7, rem = hwid >> 3;
    const int wgid = (xcd < r ? xcd * (q + 1) : r * (q + 1) + (xcd - r) * q) + rem;
    const int brow = wgid % gx, bcol = wgid / gx;

    const int w = tid >> 6, lane = tid & 63;
    const int wr = w >> 1, wc = w & 1;
    const int lg = lane >> 4, lr = lane & 15;

    f32x4 acc[4][4] = {};

    // staging: wave w stages rows [32w,32w+32); lane->row w*32+(lane>>2), col8=(lane&3)*8
    const int srow = w * 32 + (lane >> 2);
    const int scol = (lane & 3) << 3;
    const u16* gA = A + (size_t)(brow * 128 + srow) * K + scol;
    const u16* gB = BT + (size_t)(bcol * 128 + srow) * K + scol;
    const size_t koff16 = (size_t)16 * K;
    const int lofs0 = (w * 32) * 32;
    const int lofs1 = (w * 32 + 16) * 32;

    const int nt = K >> 5;
    // prologue: stage tile 0 into buf 0
    gload16(gA, &As[0][lofs0]);
    gload16(gA + koff16, &As[0][lofs1]);
    gload16(gB, &Bs[0][lofs0]);
    gload16(gB + koff16, &Bs[0][lofs1]);
    __syncthreads();

    int cur = 0;
    for (int t = 0; t < nt; t++) {
        if (t + 1 < nt) {
            const int kb = (t + 1) << 5;
            gload16(gA + kb, &As[cur ^ 1][lofs0]);
            gload16(gA + koff16 + kb, &As[cur ^ 1][lofs1]);
            gload16(gB + kb, &Bs[cur ^ 1][lofs0]);
            gload16(gB + koff16 + kb, &Bs[cur ^ 1][lofs1]);
        }
        bf16x8 aF[4], bF[4];
#pragma unroll
        for (int m = 0; m < 4; m++)
            aF[m] = *(const bf16x8*)(&As[cur][(wr * 64 + m * 16 + lr) * 32 + lg * 8]);
#pragma unroll
        for (int n = 0; n < 4; n++)
            bF[n] = *(const bf16x8*)(&Bs[cur][(wc * 64 + n * 16 + lr) * 32 + lg * 8]);
#pragma unroll
        for (int m = 0; m < 4; m++)
#pragma unroll
            for (int n = 0; n < 4; n++)
                acc[m][n] = __builtin_amdgcn_mfma_f32_16x16x32_bf16(aF[m], bF[n], acc[m][n], 0, 0, 0);
        __syncthreads();   // drains vmcnt (next-tile loads) + lgkmcnt (our ds_reads)
        cur ^= 1;
    }

#pragma unroll
    for (int m = 0; m < 4; m++)
#pragma unroll
        for (int n = 0; n < 4; n++)
#pragma unroll
            for (int j = 0; j < 4; j++) {
                int row = brow * 128 + wr * 64 + m * 16 + lg * 4 + j;
                int col = bcol * 128 + wc * 64 + n * 16 + lr;
                size_t idx = (size_t)row * N + col;
                float v = acc[m][n][j];
                if constexpr (OUT_BF16) {
                    ((u16*)Cp)[idx] = f2b(v);
                } else if constexpr (ADD) {
                    ((float*)Cp)[idx] = ((const float*)Cp)[idx] + v;
                } else {
                    ((float*)Cp)[idx] = v;
                }
            }
}

// ---------------- fallback GEMM (f32 B, non-transposed) — LM head only ----------------
__device__ __forceinline__ int bs_off(int c, int k) {
    return c * 40 + ((((k >> 3) ^ ((c >> 3) & 3)) << 3) | (k & 7));
}

__global__ __launch_bounds__(256) void gemm_f32b_kernel(const u16* __restrict__ A,
                                                        const float* __restrict__ B,
                                                        float* __restrict__ C,
                                                        int N, int K) {
    __shared__ __align__(16) u16 As[128 * 40];
    __shared__ __align__(16) u16 Bs[128 * 40];
    const int tid = threadIdx.x;
    const int brow = blockIdx.y, bcol = blockIdx.x;
    const int wid = tid >> 6, lane = tid & 63;
    const int wr = wid >> 1, wc = wid & 1;
    const int lg = lane >> 4, lr = lane & 15;

    f32x4 acc[4][4] = {};
    const int ar = tid >> 2, ac = (tid & 3) << 3;
    const int bk = tid >> 4, bc = (tid & 15) << 3;

    for (int kb = 0; kb < K; kb += 32) {
        {
            const u16* ga = A + (size_t)(brow * 128 + ar) * K + kb + ac;
            *(uint4*)(&As[ar * 40 + ac]) = *(const uint4*)ga;
            *(uint4*)(&As[(ar + 64) * 40 + ac]) = *(const uint4*)(ga + (size_t)64 * K);
        }
        {
            const float* gb = B + (size_t)(kb + bk) * N + bcol * 128 + bc;
            float4 a0 = *(const float4*)gb;
            float4 a1 = *(const float4*)(gb + 4);
            float4 b0 = *(const float4*)(gb + (size_t)16 * N);
            float4 b1 = *(const float4*)(gb + (size_t)16 * N + 4);
            float f0[8] = {a0.x, a0.y, a0.z, a0.w, a1.x, a1.y, a1.z, a1.w};
            float f1[8] = {b0.x, b0.y, b0.z, b0.w, b1.x, b1.y, b1.z, b1.w};
#pragma unroll
            for (int i = 0; i < 8; i++) {
                Bs[bs_off(bc + i, bk)] = f2b(f0[i]);
                Bs[bs_off(bc + i, bk + 16)] = f2b(f1[i]);
            }
        }
        __syncthreads();

        bf16x8 aF[4], bF[4];
#pragma unroll
        for (int m = 0; m < 4; m++)
            aF[m] = *(const bf16x8*)(&As[(wr * 64 + m * 16 + lr) * 40 + lg * 8]);
#pragma unroll
        for (int n = 0; n < 4; n++) {
            int c = wc * 64 + n * 16 + lr;
            bF[n] = *(const bf16x8*)(&Bs[c * 40 + ((lg ^ ((c >> 3) & 3)) << 3)]);
        }
#pragma unroll
        for (int m = 0; m < 4; m++)
#pragma unroll
            for (int n = 0; n < 4; n++)
                acc[m][n] = __builtin_amdgcn_mfma_f32_16x16x32_bf16(aF[m], bF[n], acc[m][n], 0, 0, 0);
        __syncthreads();
    }

#pragma unroll
    for (int m = 0; m < 4; m++)
#pragma unroll
        for (int n = 0; n < 4; n++)
#pragma unroll
            for (int j = 0; j < 4; j++) {
                int row = brow * 128 + wr * 64 + m * 16 + lg * 4 + j;
                int col = bcol * 128 + wc * 64 + n * 16 + lr;
                C[(size_t)row * N + col] = acc[m][n][j];
            }
}

// ---------------- RoPE: bf16 strided in -> bf16 packed out ----------------
__global__ __launch_bounds__(256) void rope_kernel(const u16* __restrict__ in,
                                                   u16* __restrict__ out, int heads,
                                                   int instride, int incoloff) {
    int idx = blockIdx.x * 256 + threadIdx.x;
    int total = T_SEQ * heads * 32;
    if (idx >= total) return;
    int i = idx & 31;
    int rest = idx >> 5;       // t*heads + h
    int t = rest / heads, hh = rest - t * heads;
    float inv = expf(-(float)i * (9.210340371976184f / 32.0f));
    float ang = (float)t * inv;
    float c = cosf(ang), s = sinf(ang);
    size_t src = (size_t)t * instride + incoloff + hh * HEAD_DIM + 2 * i;
    size_t dst = (size_t)rest * HEAD_DIM + 2 * i;
    float x0 = b2f(in[src]), x1 = b2f(in[src + 1]);
    out[dst]     = f2b(x0 * c - x1 * s);
    out[dst + 1] = f2b(x0 * s + x1 * c);
}

// ---------------- flash attention ----------------
__global__ __launch_bounds__(256) void fattn_kernel(const u16* __restrict__ q,
                                                    const u16* __restrict__ k,
                                                    const u16* __restrict__ vt,
                                                    u16* __restrict__ out) {
    __shared__ __align__(16) u16 Ks[KBLK * KSS];
    __shared__ __align__(16) u16 Vt[HEAD_DIM * VTS];
    __shared__ __align__(16) u16 Ps[QBLK * PSS];
    const int tid = threadIdx.x;
    const int qb0 = blockIdx.x * QBLK, h = blockIdx.y, kvh = h >> 2;
    const int w = tid >> 6, lane = tid & 63;
    const int lg = lane >> 4, lr = lane & 15;

    bf16x8 qf0, qf1;
    {
        const u16* src = q + ((size_t)(qb0 + w * 16 + lr) * NH + h) * HEAD_DIM;
        qf0 = *(const bf16x8*)(src + lg * 8);
        qf1 = *(const bf16x8*)(src + 32 + lg * 8);
    }

    f32x4 acc_o[4] = {};
    float m_run[4] = {-1e30f, -1e30f, -1e30f, -1e30f};
    float l_run[4] = {0.f, 0.f, 0.f, 0.f};

    const int ntiles = (qb0 + QBLK - 1) / KBLK + 1;

    for (int kt = 0; kt < ntiles; kt++) {
        const int kb = kt * KBLK;
        __syncthreads();
        for (int c = tid; c < KBLK * 8; c += 256) {
            int row = c >> 3, c8 = (c & 7) << 3;
            *(uint4*)(&Ks[row * KSS + c8]) =
                *(const uint4*)(k + ((size_t)(kb + row) * NKV + kvh) * HEAD_DIM + c8);
        }
        for (int c = tid; c < HEAD_DIM * 16; c += 256) {
            int d = c >> 4, c16 = (c & 15) << 3;
            *(uint4*)(&Vt[d * VTS + c16]) =
                *(const uint4*)(vt + (size_t)(kvh * HEAD_DIM + d) * T_SEQ + kb + c16);
        }
        __syncthreads();

        f32x4 s[8] = {};
#pragma unroll
        for (int n = 0; n < 8; n++) {
            bf16x8 kf0 = *(const bf16x8*)(&Ks[(n * 16 + lr) * KSS + lg * 8]);
            bf16x8 kf1 = *(const bf16x8*)(&Ks[(n * 16 + lr) * KSS + 32 + lg * 8]);
            s[n] = __builtin_amdgcn_mfma_f32_16x16x32_bf16(qf0, kf0, s[n], 0, 0, 0);
            s[n] = __builtin_amdgcn_mfma_f32_16x16x32_bf16(qf1, kf1, s[n], 0, 0, 0);
        }

#pragma unroll
        for (int j = 0; j < 4; j++) {
            int q_g = qb0 + w * 16 + lg * 4 + j;
            float sv[8];
            float tmax = -1e30f;
#pragma unroll
            for (int n = 0; n < 8; n++) {
                float xx = s[n][j] * 0.125f;
                if (kb + n * 16 + lr > q_g) xx = -1e30f;
                sv[n] = xx;
                tmax = fmaxf(tmax, xx);
            }
#pragma unroll
            for (int mm = 1; mm < 16; mm <<= 1) tmax = fmaxf(tmax, __shfl_xor(tmax, mm));
            float mn = fmaxf(m_run[j], tmax);
            float sc = __expf(m_run[j] - mn);
            m_run[j] = mn;
            float rsum = 0.f;
#pragma unroll
            for (int n = 0; n < 8; n++) {
                float p = __expf(sv[n] - mn);
                rsum += p;
                Ps[(w * 16 + lg * 4 + j) * PSS + n * 16 + lr] = f2b(p);
            }
#pragma unroll
            for (int mm = 1; mm < 16; mm <<= 1) rsum += __shfl_xor(rsum, mm);
            l_run[j] = l_run[j] * sc + rsum;
#pragma unroll
            for (int n = 0; n < 4; n++) acc_o[n][j] *= sc;
        }

#pragma unroll
        for (int ks = 0; ks < 4; ks++) {
            bf16x8 pf = *(const bf16x8*)(&Ps[(w * 16 + lr) * PSS + ks * 32 + lg * 8]);
#pragma unroll
            for (int n = 0; n < 4; n++) {
                bf16x8 vf = *(const bf16x8*)(&Vt[(n * 16 + lr) * VTS + ks * 32 + lg * 8]);
                acc_o[n] = __builtin_amdgcn_mfma_f32_16x16x32_bf16(pf, vf, acc_o[n], 0, 0, 0);
            }
        }
    }

#pragma unroll
    for (int n = 0; n < 4; n++)
#pragma unroll
        for (int j = 0; j < 4; j++) {
            int t = qb0 + w * 16 + lg * 4 + j;
            int d = n * 16 + lr;
            out[((size_t)t * NH + h) * HEAD_DIM + d] = f2b(acc_o[n][j] / l_run[j]);
        }
}

// ---------------- silu(gate)*up from packed bf16 gu[t][5632] -> bf16 [t][2816] ----------------
__global__ __launch_bounds__(256) void silu_mul_kernel(const u16* __restrict__ gu,
                                                       u16* __restrict__ out) {
    int t = blockIdx.x;
    int c = blockIdx.y * 256 + threadIdx.x;   // < 2816
    float gv = b2f(gu[(size_t)t * 5632 + c]);
    float uv = b2f(gu[(size_t)t * 5632 + 2816 + c]);
    float s = gv / (1.f + __expf(-gv));
    out[(size_t)t * FFDIM + c] = f2b(s * uv);
}

// ---------------- host launch ----------------
extern "C" void kernel_launch(void* const* d_in, const int* in_sizes, int n_in,
                              void* d_out, int out_size, void* d_ws, size_t ws_size,
                              hipStream_t stream) {
    const int*   toks = (const int*)d_in[0];
    const float* emb  = (const float*)d_in[1];
    const float* Wq   = (const float*)d_in[2];
    const float* Wk   = (const float*)d_in[3];
    const float* Wv   = (const float*)d_in[4];
    const float* Wo   = (const float*)d_in[5];
    const float* Wg   = (const float*)d_in[6];
    const float* Wu   = (const float*)d_in[7];
    const float* Wd   = (const float*)d_in[8];
    const float* ln1  = (const float*)d_in[9];
    const float* ln2  = (const float*)d_in[10];
    const float* nw   = (const float*)d_in[11];
    const float* Wlm  = (const float*)d_in[12];

    // ---- scratch layout in d_out (262MB, all dead before LM head writes) ----
    char* ob = (char*)d_out;
    const size_t MB = 1024 * 1024;
    float* x    = (float*)(ob + 0 * MB);    // 8MB   residual [T,D] f32
    u16* fqkv   = (u16*)  (ob + 8 * MB);    // 6MB   [T,1536] qkv packed bf16
    u16* fGU    = (u16*)  (ob + 16 * MB);   // 22MB  [T,5632] gate|up packed bf16
    u16* vt     = (u16*)  (ob + 40 * MB);   // 1MB   V^T [256][T]
    u16* qb     = (u16*)  (ob + 42 * MB);   // 4MB
    u16* kb     = (u16*)  (ob + 47 * MB);   // 1MB
    u16* attnb  = (u16*)  (ob + 48 * MB);   // 4MB
    u16* ffb    = (u16*)  (ob + 52 * MB);   // 11.5MB
    size_t woff = 64 * MB;                  // packed bf16 transposed weights (43MB)
    auto walloc = [&](size_t elems) {
        u16* p = (u16*)(ob + woff);
        woff += ((elems * 2 + 255) & ~(size_t)255);
        return p;
    };
    u16 *WqkvT[2], *WoT[2], *WguT[2], *WdT[2];
    for (int l = 0; l < 2; l++) {
        WqkvT[l] = walloc((size_t)1536 * DMODEL);
        WoT[l]   = walloc((size_t)DMODEL * DMODEL);
        WguT[l]  = walloc((size_t)5632 * DMODEL);
        WdT[l]   = walloc((size_t)DMODEL * FFDIM);
    }
    u16* h = (u16*)d_ws;   // 4MB bf16 [T,D]
    bool ws_big = ws_size >= 72 * MB;
    u16* WlmT = ws_big ? (u16*)((char*)d_ws + 4 * MB) : nullptr;  // [NVOCAB][DMODEL]
    (void)in_sizes; (void)n_in; (void)out_size;

    dim3 blk(256);
    auto tcast = [&](const float* in, u16* out, int K, int N) {
        tcast_kernel<<<dim3(N / 32, K / 32), blk, 0, stream>>>(in, out, K, N);
    };
    auto gemm_f32 = [&](const u16* A, const u16* BT, float* C, int N, int K, bool add) {
        dim3 g(T_SEQ / 128, N / 128);
        if (add) gemm_bt_kernel<false, true><<<g, blk, 0, stream>>>(A, BT, (void*)C, N, K);
        else     gemm_bt_kernel<false, false><<<g, blk, 0, stream>>>(A, BT, (void*)C, N, K);
    };
    auto gemm_b16 = [&](const u16* A, const u16* BT, u16* C, int N, int K) {
        dim3 g(T_SEQ / 128, N / 128);
        gemm_bt_kernel<true, false><<<g, blk, 0, stream>>>(A, BT, (void*)C, N, K);
    };

    // ---- one-time weight transpose-casts (packed) ----
    for (int l = 0; l < 2; l++) {
        tcast(Wq + (size_t)l * DMODEL * NH * HEAD_DIM,  WqkvT[l],                         DMODEL, NH * HEAD_DIM);
        tcast(Wk + (size_t)l * DMODEL * NKV * HEAD_DIM, WqkvT[l] + (size_t)1024 * DMODEL, DMODEL, NKV * HEAD_DIM);
        tcast(Wv + (size_t)l * DMODEL * NKV * HEAD_DIM, WqkvT[l] + (size_t)1280 * DMODEL, DMODEL, NKV * HEAD_DIM);
        tcast(Wo + (size_t)l * DMODEL * DMODEL,         WoT[l],  DMODEL, DMODEL);
        tcast(Wg + (size_t)l * DMODEL * FFDIM,          WguT[l],                          DMODEL, FFDIM);
        tcast(Wu + (size_t)l * DMODEL * FFDIM,          WguT[l] + (size_t)FFDIM * DMODEL, DMODEL, FFDIM);
        tcast(Wd + (size_t)l * FFDIM * DMODEL,          WdT[l],  FFDIM, DMODEL);
    }
    if (WlmT) tcast(Wlm, WlmT, DMODEL, NVOCAB);

    embed_kernel<<<dim3(T_SEQ * DMODEL / 256), blk, 0, stream>>>(toks, emb, x);

    for (int l = 0; l < 2; l++) {
        // attn block
        rmsnorm_kernel<<<dim3(T_SEQ), blk, 0, stream>>>(x, ln1 + (size_t)l * DMODEL, h);
        gemm_b16(h, WqkvT[l], fqkv, 1536, DMODEL);
        rope_kernel<<<dim3(T_SEQ * NH * 32 / 256), blk, 0, stream>>>(fqkv, qb, NH, 1536, 0);
        rope_kernel<<<dim3(T_SEQ * NKV * 32 / 256), blk, 0, stream>>>(fqkv, kb, NKV, 1536, 1024);
        vtcast_kernel<<<dim3(8, T_SEQ / 32), blk, 0, stream>>>(fqkv, vt);
        fattn_kernel<<<dim3(T_SEQ / QBLK, NH), blk, 0, stream>>>(qb, kb, vt, attnb);
        gemm_f32(attnb, WoT[l], x, DMODEL, DMODEL, true);   // fused residual add

        // ffn block
        rmsnorm_kernel<<<dim3(T_SEQ), blk, 0, stream>>>(x, ln2 + (size_t)l * DMODEL, h);
        gemm_b16(h, WguT[l], fGU, 5632, DMODEL);
        silu_mul_kernel<<<dim3(T_SEQ, FFDIM / 256), blk, 0, stream>>>(fGU, ffb);
        gemm_f32(ffb, WdT[l], x, DMODEL, FFDIM, true);      // fused residual add
    }

    // final norm + lm head
    rmsnorm_kernel<<<dim3(T_SEQ), blk, 0, stream>>>(x, nw, h);
    if (WlmT) {
        gemm_f32(h, WlmT, (float*)d_out, NVOCAB, DMODEL, false);
    } else {
        dim3 g(NVOCAB / 128, T_SEQ / 128);
        gemm_f32b_kernel<<<g, blk, 0, stream>>>(h, Wlm, (float*)d_out, NVOCAB, DMODEL);
    }
}

// Round 13
// 842.266 us; speedup vs baseline: 1.0542x; 1.0179x over previous
//
#include <hip/hip_runtime.h>

// ---------------- constants ----------------
#define T_SEQ 2048
#define DMODEL 1024
#define NH 16
#define NKV 4
#define HEAD_DIM 64
#define FFDIM 2816
#define NVOCAB 32000

// flash-attn tile params
#define QBLK 64
#define KBLK 128
#define KSS 72
#define VTS 136
#define PSS 136

using u16 = unsigned short;
typedef __bf16 bf16x8 __attribute__((ext_vector_type(8)));
typedef float f32x4 __attribute__((ext_vector_type(4)));

__device__ __forceinline__ float b2f(u16 u) {
    union { unsigned int i; float f; } v; v.i = ((unsigned int)u) << 16; return v.f;
}
__device__ __forceinline__ u16 f2b(float f) {
    unsigned int u = __builtin_bit_cast(unsigned int, f);
    unsigned int r = (u + 0x7FFFu + ((u >> 16) & 1u)) >> 16;
    return (u16)r;
}
// async global->LDS, 16B per lane; LDS dest = wave-uniform base + lane*16
__device__ __forceinline__ void gload16(const u16* g, u16* l) {
    __builtin_amdgcn_global_load_lds(
        (const __attribute__((address_space(1))) void*)g,
        (__attribute__((address_space(3))) void*)l, 16, 0, 0);
}

// ---------------- embedding gather ----------------
__global__ __launch_bounds__(256) void embed_kernel(const int* __restrict__ toks,
                                                    const float* __restrict__ emb,
                                                    float* __restrict__ x) {
    int idx = blockIdx.x * 256 + threadIdx.x;
    int t = idx >> 10, d = idx & 1023;
    x[idx] = emb[(size_t)toks[t] * DMODEL + d];
}

// ---------------- rmsnorm: f32 in -> bf16 out ----------------
__global__ __launch_bounds__(256) void rmsnorm_kernel(const float* __restrict__ x,
                                                      const float* __restrict__ w,
                                                      u16* __restrict__ out) {
    __shared__ float red[256];
    const int row = blockIdx.x, tid = threadIdx.x;
    const float* xr = x + (size_t)row * DMODEL;
    float vals[4]; float ss = 0.f;
#pragma unroll
    for (int i = 0; i < 4; i++) { float v = xr[tid + 256 * i]; vals[i] = v; ss += v * v; }
    red[tid] = ss; __syncthreads();
    for (int s = 128; s > 0; s >>= 1) { if (tid < s) red[tid] += red[tid + s]; __syncthreads(); }
    float inv = rsqrtf(red[0] * (1.0f / DMODEL) + 1e-5f);
#pragma unroll
    for (int i = 0; i < 4; i++) {
        int c = tid + 256 * i;
        out[(size_t)row * DMODEL + c] = f2b(vals[i] * inv * w[c]);
    }
}

// ---------------- transpose-cast: in[K][N] f32 -> out[N][K] bf16 ----------------
__global__ __launch_bounds__(256) void tcast_kernel(const float* __restrict__ in,
                                                    u16* __restrict__ out, int K, int N) {
    __shared__ float tile[32][33];
    int bx = blockIdx.x * 32;  // N
    int by = blockIdx.y * 32;  // K
    int tx = threadIdx.x & 31, ty = threadIdx.x >> 5;
#pragma unroll
    for (int i = 0; i < 32; i += 8)
        tile[ty + i][tx] = in[(size_t)(by + ty + i) * N + bx + tx];
    __syncthreads();
#pragma unroll
    for (int i = 0; i < 32; i += 8)
        out[(size_t)(bx + ty + i) * K + by + tx] = f2b(tile[tx][ty + i]);
}

// ---------------- strided transpose for V: fqkv[:,1280:1536](bf16) -> vt[256][T] ----------------
__global__ __launch_bounds__(256) void vtcast_kernel(const u16* __restrict__ fqkv,
                                                     u16* __restrict__ vt) {
    __shared__ u16 tile[32][33];
    int bx = blockIdx.x * 32;  // v-dim (0..255)
    int by = blockIdx.y * 32;  // t
    int tx = threadIdx.x & 31, ty = threadIdx.x >> 5;
#pragma unroll
    for (int i = 0; i < 32; i += 8)
        tile[ty + i][tx] = fqkv[(size_t)(by + ty + i) * 1536 + 1280 + bx + tx];
    __syncthreads();
#pragma unroll
    for (int i = 0; i < 32; i += 8)
        vt[(size_t)(bx + ty + i) * T_SEQ + by + tx] = tile[tx][ty + i];
}

// ---------------- GEMM-BT 128x128 (2-phase, proven): C = A * BT^T ----------------
template<bool OUT_BF16, bool ADD>
__global__ __launch_bounds__(256) void gemm_bt_kernel(const u16* __restrict__ A,
                                                      const u16* __restrict__ BT,
                                                      void* __restrict__ Cp,
                                                      int N, int K) {
    __shared__ __align__(16) u16 As[2][128 * 32];
    __shared__ __align__(16) u16 Bs[2][128 * 32];
    const int tid = threadIdx.x;
    const int gx = gridDim.x;
    const int nwg = gx * gridDim.y;
    const int hwid = blockIdx.y * gx + blockIdx.x;
    const int q = nwg >> 3, r = nwg & 7;
    const int xcd = hwid & 7, rem = hwid >> 3;
    const int wgid = (xcd < r ? xcd * (q + 1) : r * (q + 1) + (xcd - r) * q) + rem;
    const int brow = wgid % gx, bcol = wgid / gx;

    const int w = tid >> 6, lane = tid & 63;
    const int wr = w >> 1, wc = w & 1;
    const int lg = lane >> 4, lr = lane & 15;

    f32x4 acc[4][4] = {};

    const int srow = w * 32 + (lane >> 2);
    const int scol = (lane & 3) << 3;
    const u16* gA = A + (size_t)(brow * 128 + srow) * K + scol;
    const u16* gB = BT + (size_t)(bcol * 128 + srow) * K + scol;
    const size_t koff16 = (size_t)16 * K;
    const int lofs0 = (w * 32) * 32;
    const int lofs1 = (w * 32 + 16) * 32;

    const int nt = K >> 5;
    gload16(gA, &As[0][lofs0]);
    gload16(gA + koff16, &As[0][lofs1]);
    gload16(gB, &Bs[0][lofs0]);
    gload16(gB + koff16, &Bs[0][lofs1]);
    __syncthreads();

    int cur = 0;
    for (int t = 0; t < nt; t++) {
        if (t + 1 < nt) {
            const int kb = (t + 1) << 5;
            gload16(gA + kb, &As[cur ^ 1][lofs0]);
            gload16(gA + koff16 + kb, &As[cur ^ 1][lofs1]);
            gload16(gB + kb, &Bs[cur ^ 1][lofs0]);
            gload16(gB + koff16 + kb, &Bs[cur ^ 1][lofs1]);
        }
        bf16x8 aF[4], bF[4];
#pragma unroll
        for (int m = 0; m < 4; m++)
            aF[m] = *(const bf16x8*)(&As[cur][(wr * 64 + m * 16 + lr) * 32 + lg * 8]);
#pragma unroll
        for (int n = 0; n < 4; n++)
            bF[n] = *(const bf16x8*)(&Bs[cur][(wc * 64 + n * 16 + lr) * 32 + lg * 8]);
#pragma unroll
        for (int m = 0; m < 4; m++)
#pragma unroll
            for (int n = 0; n < 4; n++)
                acc[m][n] = __builtin_amdgcn_mfma_f32_16x16x32_bf16(aF[m], bF[n], acc[m][n], 0, 0, 0);
        __syncthreads();
        cur ^= 1;
    }

#pragma unroll
    for (int m = 0; m < 4; m++)
#pragma unroll
        for (int n = 0; n < 4; n++)
#pragma unroll
            for (int j = 0; j < 4; j++) {
                int row = brow * 128 + wr * 64 + m * 16 + lg * 4 + j;
                int col = bcol * 128 + wc * 64 + n * 16 + lr;
                size_t idx = (size_t)row * N + col;
                float v = acc[m][n][j];
                if constexpr (OUT_BF16) {
                    ((u16*)Cp)[idx] = f2b(v);
                } else if constexpr (ADD) {
                    ((float*)Cp)[idx] = ((const float*)Cp)[idx] + v;
                } else {
                    ((float*)Cp)[idx] = v;
                }
            }
}

// ---------------- GEMM-BT 256x256, 3-buffer pipelined (LM head) ----------------
// 512 thr = 8 waves (2M x 4N); BK=32; 2 phases/tile (mg=0: m-frags 0-3; mg=1: 4-7).
// LDS 96KB dynamic: A[3buf][16 bands][1024B] @0, B same @48KB. Band = 16 rows x
// 32 cols bf16. Swizzle: rows 8-15 of each band store col-blocks XOR 2 (applied
// on gload SOURCE col; ds_read applies same XOR) -> 4-way banks instead of 8.
// Pipeline (hazard-proved): stage tile t+2 during tile t (A @phase0, B @phase1).
// WAR: buf (t+2)%3 last ds_read in tile t-1, complete before its end-barrier
// (lgkmcnt(0) precedes MFMA precedes barrier); stages issue >=1 barrier later.
// RAW: vmcnt(4) at end of tile t = tile t+1's 4 loads landed, tile t+2's 4 may
// fly; vmcnt(0) when nothing newer staged. Waits precede s_barrier so after the
// barrier ALL waves' loads landed (vmcnt is per-wave; bands are cross-wave).
__global__ __launch_bounds__(512) void gemm256_kernel(const u16* __restrict__ A,
                                                      const u16* __restrict__ BT,
                                                      float* __restrict__ C,
                                                      int N, int K) {
    extern __shared__ __align__(16) u16 lds[];
    const int tid = threadIdx.x;
    const int gx = gridDim.x;
    const int nwg = gx * gridDim.y;
    const int hwid = blockIdx.y * gx + blockIdx.x;
    const int q = nwg >> 3, r = nwg & 7;
    const int xcd = hwid & 7, rem = hwid >> 3;
    const int wgid = (xcd < r ? xcd * (q + 1) : r * (q + 1) + (xcd - r) * q) + rem;
    const int bR = wgid % gx, bC = wgid / gx;

    const int w = tid >> 6, lane = tid & 63;
    const int wm = w >> 2, wn = w & 3;
    const int lg = lane >> 4, lr = lane & 15;

    f32x4 acc[8][4] = {};

    const int srow = lane >> 2;                                    // row in band
    const int scol = ((lane & 3) ^ ((lane >= 32) ? 2 : 0)) << 3;   // swizzled src col
    const int rblk = (((lr >= 8) ? (lg ^ 2) : lg)) << 4;           // ds_read byte blk

    const u16* Ab = A + (size_t)(bR * 256) * K + scol;
    const u16* Bb = BT + (size_t)(bC * 256) * K + scol;

    auto STAGE_A = [&](int t, int b) {
        gload16(Ab + (size_t)(w * 16 + srow) * K + t * 32,
                lds + (b * 16384 + w * 1024) / 2);
        gload16(Ab + (size_t)((w + 8) * 16 + srow) * K + t * 32,
                lds + (b * 16384 + (w + 8) * 1024) / 2);
    };
    auto STAGE_B = [&](int t, int b) {
        gload16(Bb + (size_t)(w * 16 + srow) * K + t * 32,
                lds + (49152 + b * 16384 + w * 1024) / 2);
        gload16(Bb + (size_t)((w + 8) * 16 + srow) * K + t * 32,
                lds + (49152 + b * 16384 + (w + 8) * 1024) / 2);
    };

    const int nt = K >> 5;
    // prologue: tiles 0,1 -> bufs 0,1; wait tile 0 (tile 1's 4 may stay in flight)
    STAGE_A(0, 0); STAGE_B(0, 0);
    STAGE_A(1, 1); STAGE_B(1, 1);
    asm volatile("s_waitcnt vmcnt(4)" ::: "memory");
    __builtin_amdgcn_s_barrier();

    int cur = 0;
    for (int t = 0; t < nt; t++) {
        const bool st = (t + 2 < nt);
        const int nb = (cur >= 1) ? cur - 1 : cur + 2;   // (cur+2)%3
        // ---- phase 0: m-frags 0-3 ----
        {
            bf16x8 aF[4], bF[4];
#pragma unroll
            for (int mi = 0; mi < 4; mi++)
                aF[mi] = *(const bf16x8*)((const char*)lds + cur * 16384 +
                                          (wm * 8 + mi) * 1024 + lr * 64 + rblk);
#pragma unroll
            for (int n = 0; n < 4; n++)
                bF[n] = *(const bf16x8*)((const char*)lds + 49152 + cur * 16384 +
                                         (wn * 4 + n) * 1024 + lr * 64 + rblk);
            if (st) STAGE_A(t + 2, nb);
            __builtin_amdgcn_s_barrier();
            asm volatile("s_waitcnt lgkmcnt(0)" ::: "memory");
            __builtin_amdgcn_sched_barrier(0);
            __builtin_amdgcn_s_setprio(1);
#pragma unroll
            for (int mi = 0; mi < 4; mi++)
#pragma unroll
                for (int n = 0; n < 4; n++)
                    acc[mi][n] = __builtin_amdgcn_mfma_f32_16x16x32_bf16(
                        aF[mi], bF[n], acc[mi][n], 0, 0, 0);
            __builtin_amdgcn_s_setprio(0);
            __builtin_amdgcn_s_barrier();
        }
        // ---- phase 1: m-frags 4-7 ----
        {
            bf16x8 aF[4], bF[4];
#pragma unroll
            for (int mi = 0; mi < 4; mi++)
                aF[mi] = *(const bf16x8*)((const char*)lds + cur * 16384 +
                                          (wm * 8 + 4 + mi) * 1024 + lr * 64 + rblk);
#pragma unroll
            for (int n = 0; n < 4; n++)
                bF[n] = *(const bf16x8*)((const char*)lds + 49152 + cur * 16384 +
                                         (wn * 4 + n) * 1024 + lr * 64 + rblk);
            if (st) STAGE_B(t + 2, nb);
            if (t + 1 < nt) {
                if (st) asm volatile("s_waitcnt vmcnt(4)" ::: "memory");
                else    asm volatile("s_waitcnt vmcnt(0)" ::: "memory");
            }
            __builtin_amdgcn_s_barrier();
            asm volatile("s_waitcnt lgkmcnt(0)" ::: "memory");
            __builtin_amdgcn_sched_barrier(0);
            __builtin_amdgcn_s_setprio(1);
#pragma unroll
            for (int mi = 0; mi < 4; mi++)
#pragma unroll
                for (int n = 0; n < 4; n++)
                    acc[4 + mi][n] = __builtin_amdgcn_mfma_f32_16x16x32_bf16(
                        aF[mi], bF[n], acc[4 + mi][n], 0, 0, 0);
            __builtin_amdgcn_s_setprio(0);
            __builtin_amdgcn_s_barrier();
        }
        cur = (cur == 2) ? 0 : cur + 1;
    }

#pragma unroll
    for (int m = 0; m < 8; m++)
#pragma unroll
        for (int n = 0; n < 4; n++)
#pragma unroll
            for (int jj = 0; jj < 4; jj++) {
                int row = bR * 256 + wm * 128 + m * 16 + lg * 4 + jj;
                int col = bC * 256 + wn * 64 + n * 16 + lr;
                C[(size_t)row * N + col] = acc[m][n][jj];
            }
}

// ---------------- fallback GEMM (f32 B, non-transposed) — LM head only ----------------
__device__ __forceinline__ int bs_off(int c, int k) {
    return c * 40 + ((((k >> 3) ^ ((c >> 3) & 3)) << 3) | (k & 7));
}

__global__ __launch_bounds__(256) void gemm_f32b_kernel(const u16* __restrict__ A,
                                                        const float* __restrict__ B,
                                                        float* __restrict__ C,
                                                        int N, int K) {
    __shared__ __align__(16) u16 As[128 * 40];
    __shared__ __align__(16) u16 Bs[128 * 40];
    const int tid = threadIdx.x;
    const int brow = blockIdx.y, bcol = blockIdx.x;
    const int wid = tid >> 6, lane = tid & 63;
    const int wr = wid >> 1, wc = wid & 1;
    const int lg = lane >> 4, lr = lane & 15;

    f32x4 acc[4][4] = {};
    const int ar = tid >> 2, ac = (tid & 3) << 3;
    const int bk = tid >> 4, bc = (tid & 15) << 3;

    for (int kb = 0; kb < K; kb += 32) {
        {
            const u16* ga = A + (size_t)(brow * 128 + ar) * K + kb + ac;
            *(uint4*)(&As[ar * 40 + ac]) = *(const uint4*)ga;
            *(uint4*)(&As[(ar + 64) * 40 + ac]) = *(const uint4*)(ga + (size_t)64 * K);
        }
        {
            const float* gb = B + (size_t)(kb + bk) * N + bcol * 128 + bc;
            float4 a0 = *(const float4*)gb;
            float4 a1 = *(const float4*)(gb + 4);
            float4 b0 = *(const float4*)(gb + (size_t)16 * N);
            float4 b1 = *(const float4*)(gb + (size_t)16 * N + 4);
            float f0[8] = {a0.x, a0.y, a0.z, a0.w, a1.x, a1.y, a1.z, a1.w};
            float f1[8] = {b0.x, b0.y, b0.z, b0.w, b1.x, b1.y, b1.z, b1.w};
#pragma unroll
            for (int i = 0; i < 8; i++) {
                Bs[bs_off(bc + i, bk)] = f2b(f0[i]);
                Bs[bs_off(bc + i, bk + 16)] = f2b(f1[i]);
            }
        }
        __syncthreads();

        bf16x8 aF[4], bF[4];
#pragma unroll
        for (int m = 0; m < 4; m++)
            aF[m] = *(const bf16x8*)(&As[(wr * 64 + m * 16 + lr) * 40 + lg * 8]);
#pragma unroll
        for (int n = 0; n < 4; n++) {
            int c = wc * 64 + n * 16 + lr;
            bF[n] = *(const bf16x8*)(&Bs[c * 40 + ((lg ^ ((c >> 3) & 3)) << 3)]);
        }
#pragma unroll
        for (int m = 0; m < 4; m++)
#pragma unroll
            for (int n = 0; n < 4; n++)
                acc[m][n] = __builtin_amdgcn_mfma_f32_16x16x32_bf16(aF[m], bF[n], acc[m][n], 0, 0, 0);
        __syncthreads();
    }

#pragma unroll
    for (int m = 0; m < 4; m++)
#pragma unroll
        for (int n = 0; n < 4; n++)
#pragma unroll
            for (int j = 0; j < 4; j++) {
                int row = brow * 128 + wr * 64 + m * 16 + lg * 4 + j;
                int col = bcol * 128 + wc * 64 + n * 16 + lr;
                C[(size_t)row * N + col] = acc[m][n][j];
            }
}

// ---------------- RoPE: bf16 strided in -> bf16 packed out ----------------
__global__ __launch_bounds__(256) void rope_kernel(const u16* __restrict__ in,
                                                   u16* __restrict__ out, int heads,
                                                   int instride, int incoloff) {
    int idx = blockIdx.x * 256 + threadIdx.x;
    int total = T_SEQ * heads * 32;
    if (idx >= total) return;
    int i = idx & 31;
    int rest = idx >> 5;       // t*heads + h
    int t = rest / heads, hh = rest - t * heads;
    float inv = expf(-(float)i * (9.210340371976184f / 32.0f));
    float ang = (float)t * inv;
    float c = cosf(ang), s = sinf(ang);
    size_t src = (size_t)t * instride + incoloff + hh * HEAD_DIM + 2 * i;
    size_t dst = (size_t)rest * HEAD_DIM + 2 * i;
    float x0 = b2f(in[src]), x1 = b2f(in[src + 1]);
    out[dst]     = f2b(x0 * c - x1 * s);
    out[dst + 1] = f2b(x0 * s + x1 * c);
}

// ---------------- flash attention ----------------
__global__ __launch_bounds__(256) void fattn_kernel(const u16* __restrict__ q,
                                                    const u16* __restrict__ k,
                                                    const u16* __restrict__ vt,
                                                    u16* __restrict__ out) {
    __shared__ __align__(16) u16 Ks[KBLK * KSS];
    __shared__ __align__(16) u16 Vt[HEAD_DIM * VTS];
    __shared__ __align__(16) u16 Ps[QBLK * PSS];
    const int tid = threadIdx.x;
    const int qb0 = blockIdx.x * QBLK, h = blockIdx.y, kvh = h >> 2;
    const int w = tid >> 6, lane = tid & 63;
    const int lg = lane >> 4, lr = lane & 15;

    bf16x8 qf0, qf1;
    {
        const u16* src = q + ((size_t)(qb0 + w * 16 + lr) * NH + h) * HEAD_DIM;
        qf0 = *(const bf16x8*)(src + lg * 8);
        qf1 = *(const bf16x8*)(src + 32 + lg * 8);
    }

    f32x4 acc_o[4] = {};
    float m_run[4] = {-1e30f, -1e30f, -1e30f, -1e30f};
    float l_run[4] = {0.f, 0.f, 0.f, 0.f};

    const int ntiles = (qb0 + QBLK - 1) / KBLK + 1;

    for (int kt = 0; kt < ntiles; kt++) {
        const int kb = kt * KBLK;
        __syncthreads();
        for (int c = tid; c < KBLK * 8; c += 256) {
            int row = c >> 3, c8 = (c & 7) << 3;
            *(uint4*)(&Ks[row * KSS + c8]) =
                *(const uint4*)(k + ((size_t)(kb + row) * NKV + kvh) * HEAD_DIM + c8);
        }
        for (int c = tid; c < HEAD_DIM * 16; c += 256) {
            int d = c >> 4, c16 = (c & 15) << 3;
            *(uint4*)(&Vt[d * VTS + c16]) =
                *(const uint4*)(vt + (size_t)(kvh * HEAD_DIM + d) * T_SEQ + kb + c16);
        }
        __syncthreads();

        f32x4 s[8] = {};
#pragma unroll
        for (int n = 0; n < 8; n++) {
            bf16x8 kf0 = *(const bf16x8*)(&Ks[(n * 16 + lr) * KSS + lg * 8]);
            bf16x8 kf1 = *(const bf16x8*)(&Ks[(n * 16 + lr) * KSS + 32 + lg * 8]);
            s[n] = __builtin_amdgcn_mfma_f32_16x16x32_bf16(qf0, kf0, s[n], 0, 0, 0);
            s[n] = __builtin_amdgcn_mfma_f32_16x16x32_bf16(qf1, kf1, s[n], 0, 0, 0);
        }

#pragma unroll
        for (int j = 0; j < 4; j++) {
            int q_g = qb0 + w * 16 + lg * 4 + j;
            float sv[8];
            float tmax = -1e30f;
#pragma unroll
            for (int n = 0; n < 8; n++) {
                float xx = s[n][j] * 0.125f;
                if (kb + n * 16 + lr > q_g) xx = -1e30f;
                sv[n] = xx;
                tmax = fmaxf(tmax, xx);
            }
#pragma unroll
            for (int mm = 1; mm < 16; mm <<= 1) tmax = fmaxf(tmax, __shfl_xor(tmax, mm));
            float mn = fmaxf(m_run[j], tmax);
            float sc = __expf(m_run[j] - mn);
            m_run[j] = mn;
            float rsum = 0.f;
#pragma unroll
            for (int n = 0; n < 8; n++) {
                float p = __expf(sv[n] - mn);
                rsum += p;
                Ps[(w * 16 + lg * 4 + j) * PSS + n * 16 + lr] = f2b(p);
            }
#pragma unroll
            for (int mm = 1; mm < 16; mm <<= 1) rsum += __shfl_xor(rsum, mm);
            l_run[j] = l_run[j] * sc + rsum;
#pragma unroll
            for (int n = 0; n < 4; n++) acc_o[n][j] *= sc;
        }

#pragma unroll
        for (int ks = 0; ks < 4; ks++) {
            bf16x8 pf = *(const bf16x8*)(&Ps[(w * 16 + lr) * PSS + ks * 32 + lg * 8]);
#pragma unroll
            for (int n = 0; n < 4; n++) {
                bf16x8 vf = *(const bf16x8*)(&Vt[(n * 16 + lr) * VTS + ks * 32 + lg * 8]);
                acc_o[n] = __builtin_amdgcn_mfma_f32_16x16x32_bf16(pf, vf, acc_o[n], 0, 0, 0);
            }
        }
    }

#pragma unroll
    for (int n = 0; n < 4; n++)
#pragma unroll
        for (int j = 0; j < 4; j++) {
            int t = qb0 + w * 16 + lg * 4 + j;
            int d = n * 16 + lr;
            out[((size_t)t * NH + h) * HEAD_DIM + d] = f2b(acc_o[n][j] / l_run[j]);
        }
}

// ---------------- silu(gate)*up from packed bf16 gu[t][5632] -> bf16 [t][2816] ----------------
__global__ __launch_bounds__(256) void silu_mul_kernel(const u16* __restrict__ gu,
                                                       u16* __restrict__ out) {
    int t = blockIdx.x;
    int c = blockIdx.y * 256 + threadIdx.x;   // < 2816
    float gv = b2f(gu[(size_t)t * 5632 + c]);
    float uv = b2f(gu[(size_t)t * 5632 + 2816 + c]);
    float s = gv / (1.f + __expf(-gv));
    out[(size_t)t * FFDIM + c] = f2b(s * uv);
}

// ---------------- host launch ----------------
extern "C" void kernel_launch(void* const* d_in, const int* in_sizes, int n_in,
                              void* d_out, int out_size, void* d_ws, size_t ws_size,
                              hipStream_t stream) {
    const int*   toks = (const int*)d_in[0];
    const float* emb  = (const float*)d_in[1];
    const float* Wq   = (const float*)d_in[2];
    const float* Wk   = (const float*)d_in[3];
    const float* Wv   = (const float*)d_in[4];
    const float* Wo   = (const float*)d_in[5];
    const float* Wg   = (const float*)d_in[6];
    const float* Wu   = (const float*)d_in[7];
    const float* Wd   = (const float*)d_in[8];
    const float* ln1  = (const float*)d_in[9];
    const float* ln2  = (const float*)d_in[10];
    const float* nw   = (const float*)d_in[11];
    const float* Wlm  = (const float*)d_in[12];

    // ---- scratch layout in d_out (262MB, all dead before LM head writes) ----
    char* ob = (char*)d_out;
    const size_t MB = 1024 * 1024;
    float* x    = (float*)(ob + 0 * MB);    // 8MB   residual [T,D] f32
    u16* fqkv   = (u16*)  (ob + 8 * MB);    // 6MB   [T,1536] qkv packed bf16
    u16* fGU    = (u16*)  (ob + 16 * MB);   // 22MB  [T,5632] gate|up packed bf16
    u16* vt     = (u16*)  (ob + 40 * MB);   // 1MB   V^T [256][T]
    u16* qb     = (u16*)  (ob + 42 * MB);   // 4MB
    u16* kb     = (u16*)  (ob + 47 * MB);   // 1MB
    u16* attnb  = (u16*)  (ob + 48 * MB);   // 4MB
    u16* ffb    = (u16*)  (ob + 52 * MB);   // 11.5MB
    size_t woff = 64 * MB;                  // packed bf16 transposed weights (43MB)
    auto walloc = [&](size_t elems) {
        u16* p = (u16*)(ob + woff);
        woff += ((elems * 2 + 255) & ~(size_t)255);
        return p;
    };
    u16 *WqkvT[2], *WoT[2], *WguT[2], *WdT[2];
    for (int l = 0; l < 2; l++) {
        WqkvT[l] = walloc((size_t)1536 * DMODEL);
        WoT[l]   = walloc((size_t)DMODEL * DMODEL);
        WguT[l]  = walloc((size_t)5632 * DMODEL);
        WdT[l]   = walloc((size_t)DMODEL * FFDIM);
    }
    u16* h = (u16*)d_ws;   // 4MB bf16 [T,D]
    bool ws_big = ws_size >= 72 * MB;
    u16* WlmT = ws_big ? (u16*)((char*)d_ws + 4 * MB) : nullptr;  // [NVOCAB][DMODEL]
    (void)in_sizes; (void)n_in; (void)out_size;

    dim3 blk(256);
    auto tcast = [&](const float* in, u16* out, int K, int N) {
        tcast_kernel<<<dim3(N / 32, K / 32), blk, 0, stream>>>(in, out, K, N);
    };
    auto gemm_f32 = [&](const u16* A, const u16* BT, float* C, int N, int K, bool add) {
        dim3 g(T_SEQ / 128, N / 128);
        if (add) gemm_bt_kernel<false, true><<<g, blk, 0, stream>>>(A, BT, (void*)C, N, K);
        else     gemm_bt_kernel<false, false><<<g, blk, 0, stream>>>(A, BT, (void*)C, N, K);
    };
    auto gemm_b16 = [&](const u16* A, const u16* BT, u16* C, int N, int K) {
        dim3 g(T_SEQ / 128, N / 128);
        gemm_bt_kernel<true, false><<<g, blk, 0, stream>>>(A, BT, (void*)C, N, K);
    };

    // ---- one-time weight transpose-casts (packed) ----
    for (int l = 0; l < 2; l++) {
        tcast(Wq + (size_t)l * DMODEL * NH * HEAD_DIM,  WqkvT[l],                         DMODEL, NH * HEAD_DIM);
        tcast(Wk + (size_t)l * DMODEL * NKV * HEAD_DIM, WqkvT[l] + (size_t)1024 * DMODEL, DMODEL, NKV * HEAD_DIM);
        tcast(Wv + (size_t)l * DMODEL * NKV * HEAD_DIM, WqkvT[l] + (size_t)1280 * DMODEL, DMODEL, NKV * HEAD_DIM);
        tcast(Wo + (size_t)l * DMODEL * DMODEL,         WoT[l],  DMODEL, DMODEL);
        tcast(Wg + (size_t)l * DMODEL * FFDIM,          WguT[l],                          DMODEL, FFDIM);
        tcast(Wu + (size_t)l * DMODEL * FFDIM,          WguT[l] + (size_t)FFDIM * DMODEL, DMODEL, FFDIM);
        tcast(Wd + (size_t)l * FFDIM * DMODEL,          WdT[l],  FFDIM, DMODEL);
    }
    if (WlmT) tcast(Wlm, WlmT, DMODEL, NVOCAB);

    embed_kernel<<<dim3(T_SEQ * DMODEL / 256), blk, 0, stream>>>(toks, emb, x);

    for (int l = 0; l < 2; l++) {
        // attn block
        rmsnorm_kernel<<<dim3(T_SEQ), blk, 0, stream>>>(x, ln1 + (size_t)l * DMODEL, h);
        gemm_b16(h, WqkvT[l], fqkv, 1536, DMODEL);
        rope_kernel<<<dim3(T_SEQ * NH * 32 / 256), blk, 0, stream>>>(fqkv, qb, NH, 1536, 0);
        rope_kernel<<<dim3(T_SEQ * NKV * 32 / 256), blk, 0, stream>>>(fqkv, kb, NKV, 1536, 1024);
        vtcast_kernel<<<dim3(8, T_SEQ / 32), blk, 0, stream>>>(fqkv, vt);
        fattn_kernel<<<dim3(T_SEQ / QBLK, NH), blk, 0, stream>>>(qb, kb, vt, attnb);
        gemm_f32(attnb, WoT[l], x, DMODEL, DMODEL, true);   // fused residual add

        // ffn block
        rmsnorm_kernel<<<dim3(T_SEQ), blk, 0, stream>>>(x, ln2 + (size_t)l * DMODEL, h);
        gemm_b16(h, WguT[l], fGU, 5632, DMODEL);
        silu_mul_kernel<<<dim3(T_SEQ, FFDIM / 256), blk, 0, stream>>>(fGU, ffb);
        gemm_f32(ffb, WdT[l], x, DMODEL, FFDIM, true);      // fused residual add
    }

    // final norm + lm head (256x256 3-buffer pipelined kernel, 96KB dynamic LDS)
    rmsnorm_kernel<<<dim3(T_SEQ), blk, 0, stream>>>(x, nw, h);
    if (WlmT) {
        (void)hipFuncSetAttribute(reinterpret_cast<const void*>(gemm256_kernel),
                                  hipFuncAttributeMaxDynamicSharedMemorySize, 98304);
        dim3 g(T_SEQ / 256, NVOCAB / 256);
        gemm256_kernel<<<g, dim3(512), 98304, stream>>>(h, WlmT, (float*)d_out,
                                                        NVOCAB, DMODEL);
    } else {
        dim3 g(NVOCAB / 128, T_SEQ / 128);
        gemm_f32b_kernel<<<g, blk, 0, stream>>>(h, Wlm, (float*)d_out, NVOCAB, DMODEL);
    }
}

// Round 14
// 812.383 us; speedup vs baseline: 1.0930x; 1.0368x over previous
//
#include <hip/hip_runtime.h>

// ---------------- constants ----------------
#define T_SEQ 2048
#define DMODEL 1024
#define NH 16
#define NKV 4
#define HEAD_DIM 64
#define FFDIM 2816
#define NVOCAB 32000

// flash-attn tile params
#define QBLK 64
#define KBLK 128
#define KSS 72
#define VTS 136
#define PSS 136

using u16 = unsigned short;
typedef __bf16 bf16x8 __attribute__((ext_vector_type(8)));
typedef float f32x4 __attribute__((ext_vector_type(4)));

__device__ __forceinline__ float b2f(u16 u) {
    union { unsigned int i; float f; } v; v.i = ((unsigned int)u) << 16; return v.f;
}
__device__ __forceinline__ u16 f2b(float f) {
    unsigned int u = __builtin_bit_cast(unsigned int, f);
    unsigned int r = (u + 0x7FFFu + ((u >> 16) & 1u)) >> 16;
    return (u16)r;
}
// async global->LDS, 16B per lane; LDS dest = wave-uniform base + lane*16
__device__ __forceinline__ void gload16(const u16* g, u16* l) {
    __builtin_amdgcn_global_load_lds(
        (const __attribute__((address_space(1))) void*)g,
        (__attribute__((address_space(3))) void*)l, 16, 0, 0);
}

// ---------------- embed + rmsnorm fused (layer 0): block = row ----------------
__global__ __launch_bounds__(256) void embed_rms_kernel(const int* __restrict__ toks,
                                                        const float* __restrict__ emb,
                                                        const float* __restrict__ w,
                                                        float* __restrict__ x,
                                                        u16* __restrict__ h) {
    __shared__ float red[256];
    const int row = blockIdx.x, tid = threadIdx.x;
    const float* er = emb + (size_t)toks[row] * DMODEL;
    float vals[4]; float ss = 0.f;
#pragma unroll
    for (int i = 0; i < 4; i++) {
        float v = er[tid + 256 * i];
        vals[i] = v; ss += v * v;
        x[(size_t)row * DMODEL + tid + 256 * i] = v;
    }
    red[tid] = ss; __syncthreads();
    for (int s = 128; s > 0; s >>= 1) { if (tid < s) red[tid] += red[tid + s]; __syncthreads(); }
    float inv = rsqrtf(red[0] * (1.0f / DMODEL) + 1e-5f);
#pragma unroll
    for (int i = 0; i < 4; i++) {
        int c = tid + 256 * i;
        h[(size_t)row * DMODEL + c] = f2b(vals[i] * inv * w[c]);
    }
}

// ---------------- rmsnorm: f32 in -> bf16 out ----------------
__global__ __launch_bounds__(256) void rmsnorm_kernel(const float* __restrict__ x,
                                                      const float* __restrict__ w,
                                                      u16* __restrict__ out) {
    __shared__ float red[256];
    const int row = blockIdx.x, tid = threadIdx.x;
    const float* xr = x + (size_t)row * DMODEL;
    float vals[4]; float ss = 0.f;
#pragma unroll
    for (int i = 0; i < 4; i++) { float v = xr[tid + 256 * i]; vals[i] = v; ss += v * v; }
    red[tid] = ss; __syncthreads();
    for (int s = 128; s > 0; s >>= 1) { if (tid < s) red[tid] += red[tid + s]; __syncthreads(); }
    float inv = rsqrtf(red[0] * (1.0f / DMODEL) + 1e-5f);
#pragma unroll
    for (int i = 0; i < 4; i++) {
        int c = tid + 256 * i;
        out[(size_t)row * DMODEL + c] = f2b(vals[i] * inv * w[c]);
    }
}

// ---------------- transpose-cast: in[K][N] f32 -> out[N][K] bf16, z = layer ----------------
__global__ __launch_bounds__(256) void tcast_kernel(const float* __restrict__ in,
                                                    u16* __restrict__ out, int K, int N,
                                                    size_t in_ls, size_t out_ls) {
    __shared__ float tile[32][33];
    in += (size_t)blockIdx.z * in_ls;
    out += (size_t)blockIdx.z * out_ls;
    int bx = blockIdx.x * 32;  // N
    int by = blockIdx.y * 32;  // K
    int tx = threadIdx.x & 31, ty = threadIdx.x >> 5;
#pragma unroll
    for (int i = 0; i < 32; i += 8)
        tile[ty + i][tx] = in[(size_t)(by + ty + i) * N + bx + tx];
    __syncthreads();
#pragma unroll
    for (int i = 0; i < 32; i += 8)
        out[(size_t)(bx + ty + i) * K + by + tx] = f2b(tile[tx][ty + i]);
}

// ---------------- fused rope(q) + rope(k) + V-transpose ----------------
// grid.x = 4096 (q-rope) + 1024 (k-rope) + 512 (vt transpose tiles)
__global__ __launch_bounds__(256) void ropeall_kernel(const u16* __restrict__ fqkv,
                                                      u16* __restrict__ qb,
                                                      u16* __restrict__ kb,
                                                      u16* __restrict__ vt) {
    __shared__ u16 tile[32][33];
    const int bid = blockIdx.x, tid = threadIdx.x;
    if (bid < 5120) {
        // rope: q section (heads=16, coloff 0) or k section (heads=4, coloff 1024)
        int heads, coloff, idx;
        u16* out;
        if (bid < 4096) { heads = NH; coloff = 0; out = qb; idx = bid * 256 + tid; }
        else            { heads = NKV; coloff = 1024; out = kb; idx = (bid - 4096) * 256 + tid; }
        int i = idx & 31;
        int rest = idx >> 5;       // t*heads + h
        int t = rest / heads, hh = rest - t * heads;
        float inv = expf(-(float)i * (9.210340371976184f / 32.0f));
        float ang = (float)t * inv;
        float c = cosf(ang), s = sinf(ang);
        size_t src = (size_t)t * 1536 + coloff + hh * HEAD_DIM + 2 * i;
        size_t dst = (size_t)rest * HEAD_DIM + 2 * i;
        float x0 = b2f(fqkv[src]), x1 = b2f(fqkv[src + 1]);
        out[dst]     = f2b(x0 * c - x1 * s);
        out[dst + 1] = f2b(x0 * s + x1 * c);
    } else {
        // V transpose: fqkv[:,1280:1536] -> vt[256][T]
        int b2 = bid - 5120;
        int bx = (b2 & 7) * 32;    // v-dim
        int by = (b2 >> 3) * 32;   // t
        int tx = tid & 31, ty = tid >> 5;
#pragma unroll
        for (int i = 0; i < 32; i += 8)
            tile[ty + i][tx] = fqkv[(size_t)(by + ty + i) * 1536 + 1280 + bx + tx];
        __syncthreads();
#pragma unroll
        for (int i = 0; i < 32; i += 8)
            vt[(size_t)(bx + ty + i) * T_SEQ + by + tx] = tile[tx][ty + i];
    }
}

// ---------------- GEMM-BT 128x128 (2-phase, proven): C = A * BT^T ----------------
template<bool OUT_BF16, bool ADD>
__global__ __launch_bounds__(256) void gemm_bt_kernel(const u16* __restrict__ A,
                                                      const u16* __restrict__ BT,
                                                      void* __restrict__ Cp,
                                                      int N, int K) {
    __shared__ __align__(16) u16 As[2][128 * 32];
    __shared__ __align__(16) u16 Bs[2][128 * 32];
    const int tid = threadIdx.x;
    const int gx = gridDim.x;
    const int nwg = gx * gridDim.y;
    const int hwid = blockIdx.y * gx + blockIdx.x;
    const int q = nwg >> 3, r = nwg & 7;
    const int xcd = hwid & 7, rem = hwid >> 3;
    const int wgid = (xcd < r ? xcd * (q + 1) : r * (q + 1) + (xcd - r) * q) + rem;
    const int brow = wgid % gx, bcol = wgid / gx;

    const int w = tid >> 6, lane = tid & 63;
    const int wr = w >> 1, wc = w & 1;
    const int lg = lane >> 4, lr = lane & 15;

    f32x4 acc[4][4] = {};

    const int srow = w * 32 + (lane >> 2);
    const int scol = (lane & 3) << 3;
    const u16* gA = A + (size_t)(brow * 128 + srow) * K + scol;
    const u16* gB = BT + (size_t)(bcol * 128 + srow) * K + scol;
    const size_t koff16 = (size_t)16 * K;
    const int lofs0 = (w * 32) * 32;
    const int lofs1 = (w * 32 + 16) * 32;

    const int nt = K >> 5;
    gload16(gA, &As[0][lofs0]);
    gload16(gA + koff16, &As[0][lofs1]);
    gload16(gB, &Bs[0][lofs0]);
    gload16(gB + koff16, &Bs[0][lofs1]);
    __syncthreads();

    int cur = 0;
    for (int t = 0; t < nt; t++) {
        if (t + 1 < nt) {
            const int kb = (t + 1) << 5;
            gload16(gA + kb, &As[cur ^ 1][lofs0]);
            gload16(gA + koff16 + kb, &As[cur ^ 1][lofs1]);
            gload16(gB + kb, &Bs[cur ^ 1][lofs0]);
            gload16(gB + koff16 + kb, &Bs[cur ^ 1][lofs1]);
        }
        bf16x8 aF[4], bF[4];
#pragma unroll
        for (int m = 0; m < 4; m++)
            aF[m] = *(const bf16x8*)(&As[cur][(wr * 64 + m * 16 + lr) * 32 + lg * 8]);
#pragma unroll
        for (int n = 0; n < 4; n++)
            bF[n] = *(const bf16x8*)(&Bs[cur][(wc * 64 + n * 16 + lr) * 32 + lg * 8]);
#pragma unroll
        for (int m = 0; m < 4; m++)
#pragma unroll
            for (int n = 0; n < 4; n++)
                acc[m][n] = __builtin_amdgcn_mfma_f32_16x16x32_bf16(aF[m], bF[n], acc[m][n], 0, 0, 0);
        __syncthreads();
        cur ^= 1;
    }

#pragma unroll
    for (int m = 0; m < 4; m++)
#pragma unroll
        for (int n = 0; n < 4; n++)
#pragma unroll
            for (int j = 0; j < 4; j++) {
                int row = brow * 128 + wr * 64 + m * 16 + lg * 4 + j;
                int col = bcol * 128 + wc * 64 + n * 16 + lr;
                size_t idx = (size_t)row * N + col;
                float v = acc[m][n][j];
                if constexpr (OUT_BF16) {
                    ((u16*)Cp)[idx] = f2b(v);
                } else if constexpr (ADD) {
                    ((float*)Cp)[idx] = ((const float*)Cp)[idx] + v;
                } else {
                    ((float*)Cp)[idx] = v;
                }
            }
}

// ---------------- GEMM-BT 256x256, 3-buffer pipelined (LM head) ----------------
// Round-13 structure (verified: conflicts=0, correct) + bF-reuse: bF read once
// per tile in phase 0, reused from registers in phase 1 (buf cur not
// overwritten until t+2, which stages into (cur+2)%3). LDS reads/phase 8->6 avg.
__global__ __launch_bounds__(512) void gemm256_kernel(const u16* __restrict__ A,
                                                      const u16* __restrict__ BT,
                                                      float* __restrict__ C,
                                                      int N, int K) {
    extern __shared__ __align__(16) u16 lds[];
    const int tid = threadIdx.x;
    const int gx = gridDim.x;
    const int nwg = gx * gridDim.y;
    const int hwid = blockIdx.y * gx + blockIdx.x;
    const int q = nwg >> 3, r = nwg & 7;
    const int xcd = hwid & 7, rem = hwid >> 3;
    const int wgid = (xcd < r ? xcd * (q + 1) : r * (q + 1) + (xcd - r) * q) + rem;
    const int bR = wgid % gx, bC = wgid / gx;

    const int w = tid >> 6, lane = tid & 63;
    const int wm = w >> 2, wn = w & 3;
    const int lg = lane >> 4, lr = lane & 15;

    f32x4 acc[8][4] = {};

    const int srow = lane >> 2;                                    // row in band
    const int scol = ((lane & 3) ^ ((lane >= 32) ? 2 : 0)) << 3;   // swizzled src col
    const int rblk = (((lr >= 8) ? (lg ^ 2) : lg)) << 4;           // ds_read byte blk

    const u16* Ab = A + (size_t)(bR * 256) * K + scol;
    const u16* Bb = BT + (size_t)(bC * 256) * K + scol;

    auto STAGE_A = [&](int t, int b) {
        gload16(Ab + (size_t)(w * 16 + srow) * K + t * 32,
                lds + (b * 16384 + w * 1024) / 2);
        gload16(Ab + (size_t)((w + 8) * 16 + srow) * K + t * 32,
                lds + (b * 16384 + (w + 8) * 1024) / 2);
    };
    auto STAGE_B = [&](int t, int b) {
        gload16(Bb + (size_t)(w * 16 + srow) * K + t * 32,
                lds + (49152 + b * 16384 + w * 1024) / 2);
        gload16(Bb + (size_t)((w + 8) * 16 + srow) * K + t * 32,
                lds + (49152 + b * 16384 + (w + 8) * 1024) / 2);
    };

    const int nt = K >> 5;
    // prologue: tiles 0,1 -> bufs 0,1; wait tile 0 (tile 1's 4 may stay in flight)
    STAGE_A(0, 0); STAGE_B(0, 0);
    STAGE_A(1, 1); STAGE_B(1, 1);
    asm volatile("s_waitcnt vmcnt(4)" ::: "memory");
    __builtin_amdgcn_s_barrier();

    int cur = 0;
    for (int t = 0; t < nt; t++) {
        const bool st = (t + 2 < nt);
        const int nb = (cur >= 1) ? cur - 1 : cur + 2;   // (cur+2)%3
        bf16x8 bF[4];
        // ---- phase 0: m-frags 0-3 (reads bF for the whole tile) ----
        {
            bf16x8 aF[4];
#pragma unroll
            for (int mi = 0; mi < 4; mi++)
                aF[mi] = *(const bf16x8*)((const char*)lds + cur * 16384 +
                                          (wm * 8 + mi) * 1024 + lr * 64 + rblk);
#pragma unroll
            for (int n = 0; n < 4; n++)
                bF[n] = *(const bf16x8*)((const char*)lds + 49152 + cur * 16384 +
                                         (wn * 4 + n) * 1024 + lr * 64 + rblk);
            if (st) STAGE_A(t + 2, nb);
            __builtin_amdgcn_s_barrier();
            asm volatile("s_waitcnt lgkmcnt(0)" ::: "memory");
            __builtin_amdgcn_sched_barrier(0);
            __builtin_amdgcn_s_setprio(1);
#pragma unroll
            for (int mi = 0; mi < 4; mi++)
#pragma unroll
                for (int n = 0; n < 4; n++)
                    acc[mi][n] = __builtin_amdgcn_mfma_f32_16x16x32_bf16(
                        aF[mi], bF[n], acc[mi][n], 0, 0, 0);
            __builtin_amdgcn_s_setprio(0);
            __builtin_amdgcn_s_barrier();
        }
        // ---- phase 1: m-frags 4-7 (reuses bF registers) ----
        {
            bf16x8 aF[4];
#pragma unroll
            for (int mi = 0; mi < 4; mi++)
                aF[mi] = *(const bf16x8*)((const char*)lds + cur * 16384 +
                                          (wm * 8 + 4 + mi) * 1024 + lr * 64 + rblk);
            if (st) STAGE_B(t + 2, nb);
            if (t + 1 < nt) {
                if (st) asm volatile("s_waitcnt vmcnt(4)" ::: "memory");
                else    asm volatile("s_waitcnt vmcnt(0)" ::: "memory");
            }
            __builtin_amdgcn_s_barrier();
            asm volatile("s_waitcnt lgkmcnt(0)" ::: "memory");
            __builtin_amdgcn_sched_barrier(0);
            __builtin_amdgcn_s_setprio(1);
#pragma unroll
            for (int mi = 0; mi < 4; mi++)
#pragma unroll
                for (int n = 0; n < 4; n++)
                    acc[4 + mi][n] = __builtin_amdgcn_mfma_f32_16x16x32_bf16(
                        aF[mi], bF[n], acc[4 + mi][n], 0, 0, 0);
            __builtin_amdgcn_s_setprio(0);
            __builtin_amdgcn_s_barrier();
        }
        cur = (cur == 2) ? 0 : cur + 1;
    }

#pragma unroll
    for (int m = 0; m < 8; m++)
#pragma unroll
        for (int n = 0; n < 4; n++)
#pragma unroll
            for (int jj = 0; jj < 4; jj++) {
                int row = bR * 256 + wm * 128 + m * 16 + lg * 4 + jj;
                int col = bC * 256 + wn * 64 + n * 16 + lr;
                C[(size_t)row * N + col] = acc[m][n][jj];
            }
}

// ---------------- fallback GEMM (f32 B, non-transposed) — LM head only ----------------
__device__ __forceinline__ int bs_off(int c, int k) {
    return c * 40 + ((((k >> 3) ^ ((c >> 3) & 3)) << 3) | (k & 7));
}

__global__ __launch_bounds__(256) void gemm_f32b_kernel(const u16* __restrict__ A,
                                                        const float* __restrict__ B,
                                                        float* __restrict__ C,
                                                        int N, int K) {
    __shared__ __align__(16) u16 As[128 * 40];
    __shared__ __align__(16) u16 Bs[128 * 40];
    const int tid = threadIdx.x;
    const int brow = blockIdx.y, bcol = blockIdx.x;
    const int wid = tid >> 6, lane = tid & 63;
    const int wr = wid >> 1, wc = wid & 1;
    const int lg = lane >> 4, lr = lane & 15;

    f32x4 acc[4][4] = {};
    const int ar = tid >> 2, ac = (tid & 3) << 3;
    const int bk = tid >> 4, bc = (tid & 15) << 3;

    for (int kb = 0; kb < K; kb += 32) {
        {
            const u16* ga = A + (size_t)(brow * 128 + ar) * K + kb + ac;
            *(uint4*)(&As[ar * 40 + ac]) = *(const uint4*)ga;
            *(uint4*)(&As[(ar + 64) * 40 + ac]) = *(const uint4*)(ga + (size_t)64 * K);
        }
        {
            const float* gb = B + (size_t)(kb + bk) * N + bcol * 128 + bc;
            float4 a0 = *(const float4*)gb;
            float4 a1 = *(const float4*)(gb + 4);
            float4 b0 = *(const float4*)(gb + (size_t)16 * N);
            float4 b1 = *(const float4*)(gb + (size_t)16 * N + 4);
            float f0[8] = {a0.x, a0.y, a0.z, a0.w, a1.x, a1.y, a1.z, a1.w};
            float f1[8] = {b0.x, b0.y, b0.z, b0.w, b1.x, b1.y, b1.z, b1.w};
#pragma unroll
            for (int i = 0; i < 8; i++) {
                Bs[bs_off(bc + i, bk)] = f2b(f0[i]);
                Bs[bs_off(bc + i, bk + 16)] = f2b(f1[i]);
            }
        }
        __syncthreads();

        bf16x8 aF[4], bF[4];
#pragma unroll
        for (int m = 0; m < 4; m++)
            aF[m] = *(const bf16x8*)(&As[(wr * 64 + m * 16 + lr) * 40 + lg * 8]);
#pragma unroll
        for (int n = 0; n < 4; n++) {
            int c = wc * 64 + n * 16 + lr;
            bF[n] = *(const bf16x8*)(&Bs[c * 40 + ((lg ^ ((c >> 3) & 3)) << 3)]);
        }
#pragma unroll
        for (int m = 0; m < 4; m++)
#pragma unroll
            for (int n = 0; n < 4; n++)
                acc[m][n] = __builtin_amdgcn_mfma_f32_16x16x32_bf16(aF[m], bF[n], acc[m][n], 0, 0, 0);
        __syncthreads();
    }

#pragma unroll
    for (int m = 0; m < 4; m++)
#pragma unroll
        for (int n = 0; n < 4; n++)
#pragma unroll
            for (int j = 0; j < 4; j++) {
                int row = brow * 128 + wr * 64 + m * 16 + lg * 4 + j;
                int col = bcol * 128 + wc * 64 + n * 16 + lr;
                C[(size_t)row * N + col] = acc[m][n][j];
            }
}

// ---------------- flash attention ----------------
__global__ __launch_bounds__(256) void fattn_kernel(const u16* __restrict__ q,
                                                    const u16* __restrict__ k,
                                                    const u16* __restrict__ vt,
                                                    u16* __restrict__ out) {
    __shared__ __align__(16) u16 Ks[KBLK * KSS];
    __shared__ __align__(16) u16 Vt[HEAD_DIM * VTS];
    __shared__ __align__(16) u16 Ps[QBLK * PSS];
    const int tid = threadIdx.x;
    const int qb0 = blockIdx.x * QBLK, h = blockIdx.y, kvh = h >> 2;
    const int w = tid >> 6, lane = tid & 63;
    const int lg = lane >> 4, lr = lane & 15;

    bf16x8 qf0, qf1;
    {
        const u16* src = q + ((size_t)(qb0 + w * 16 + lr) * NH + h) * HEAD_DIM;
        qf0 = *(const bf16x8*)(src + lg * 8);
        qf1 = *(const bf16x8*)(src + 32 + lg * 8);
    }

    f32x4 acc_o[4] = {};
    float m_run[4] = {-1e30f, -1e30f, -1e30f, -1e30f};
    float l_run[4] = {0.f, 0.f, 0.f, 0.f};

    const int ntiles = (qb0 + QBLK - 1) / KBLK + 1;

    for (int kt = 0; kt < ntiles; kt++) {
        const int kb = kt * KBLK;
        __syncthreads();
        for (int c = tid; c < KBLK * 8; c += 256) {
            int row = c >> 3, c8 = (c & 7) << 3;
            *(uint4*)(&Ks[row * KSS + c8]) =
                *(const uint4*)(k + ((size_t)(kb + row) * NKV + kvh) * HEAD_DIM + c8);
        }
        for (int c = tid; c < HEAD_DIM * 16; c += 256) {
            int d = c >> 4, c16 = (c & 15) << 3;
            *(uint4*)(&Vt[d * VTS + c16]) =
                *(const uint4*)(vt + (size_t)(kvh * HEAD_DIM + d) * T_SEQ + kb + c16);
        }
        __syncthreads();

        f32x4 s[8] = {};
#pragma unroll
        for (int n = 0; n < 8; n++) {
            bf16x8 kf0 = *(const bf16x8*)(&Ks[(n * 16 + lr) * KSS + lg * 8]);
            bf16x8 kf1 = *(const bf16x8*)(&Ks[(n * 16 + lr) * KSS + 32 + lg * 8]);
            s[n] = __builtin_amdgcn_mfma_f32_16x16x32_bf16(qf0, kf0, s[n], 0, 0, 0);
            s[n] = __builtin_amdgcn_mfma_f32_16x16x32_bf16(qf1, kf1, s[n], 0, 0, 0);
        }

#pragma unroll
        for (int j = 0; j < 4; j++) {
            int q_g = qb0 + w * 16 + lg * 4 + j;
            float sv[8];
            float tmax = -1e30f;
#pragma unroll
            for (int n = 0; n < 8; n++) {
                float xx = s[n][j] * 0.125f;
                if (kb + n * 16 + lr > q_g) xx = -1e30f;
                sv[n] = xx;
                tmax = fmaxf(tmax, xx);
            }
#pragma unroll
            for (int mm = 1; mm < 16; mm <<= 1) tmax = fmaxf(tmax, __shfl_xor(tmax, mm));
            float mn = fmaxf(m_run[j], tmax);
            float sc = __expf(m_run[j] - mn);
            m_run[j] = mn;
            float rsum = 0.f;
#pragma unroll
            for (int n = 0; n < 8; n++) {
                float p = __expf(sv[n] - mn);
                rsum += p;
                Ps[(w * 16 + lg * 4 + j) * PSS + n * 16 + lr] = f2b(p);
            }
#pragma unroll
            for (int mm = 1; mm < 16; mm <<= 1) rsum += __shfl_xor(rsum, mm);
            l_run[j] = l_run[j] * sc + rsum;
#pragma unroll
            for (int n = 0; n < 4; n++) acc_o[n][j] *= sc;
        }

#pragma unroll
        for (int ks = 0; ks < 4; ks++) {
            bf16x8 pf = *(const bf16x8*)(&Ps[(w * 16 + lr) * PSS + ks * 32 + lg * 8]);
#pragma unroll
            for (int n = 0; n < 4; n++) {
                bf16x8 vf = *(const bf16x8*)(&Vt[(n * 16 + lr) * VTS + ks * 32 + lg * 8]);
                acc_o[n] = __builtin_amdgcn_mfma_f32_16x16x32_bf16(pf, vf, acc_o[n], 0, 0, 0);
            }
        }
    }

#pragma unroll
    for (int n = 0; n < 4; n++)
#pragma unroll
        for (int j = 0; j < 4; j++) {
            int t = qb0 + w * 16 + lg * 4 + j;
            int d = n * 16 + lr;
            out[((size_t)t * NH + h) * HEAD_DIM + d] = f2b(acc_o[n][j] / l_run[j]);
        }
}

// ---------------- silu(gate)*up from packed bf16 gu[t][5632] -> bf16 [t][2816] ----------------
__global__ __launch_bounds__(256) void silu_mul_kernel(const u16* __restrict__ gu,
                                                       u16* __restrict__ out) {
    int t = blockIdx.x;
    int c = blockIdx.y * 256 + threadIdx.x;   // < 2816
    float gv = b2f(gu[(size_t)t * 5632 + c]);
    float uv = b2f(gu[(size_t)t * 5632 + 2816 + c]);
    float s = gv / (1.f + __expf(-gv));
    out[(size_t)t * FFDIM + c] = f2b(s * uv);
}

// ---------------- host launch ----------------
extern "C" void kernel_launch(void* const* d_in, const int* in_sizes, int n_in,
                              void* d_out, int out_size, void* d_ws, size_t ws_size,
                              hipStream_t stream) {
    const int*   toks = (const int*)d_in[0];
    const float* emb  = (const float*)d_in[1];
    const float* Wq   = (const float*)d_in[2];
    const float* Wk   = (const float*)d_in[3];
    const float* Wv   = (const float*)d_in[4];
    const float* Wo   = (const float*)d_in[5];
    const float* Wg   = (const float*)d_in[6];
    const float* Wu   = (const float*)d_in[7];
    const float* Wd   = (const float*)d_in[8];
    const float* ln1  = (const float*)d_in[9];
    const float* ln2  = (const float*)d_in[10];
    const float* nw   = (const float*)d_in[11];
    const float* Wlm  = (const float*)d_in[12];

    // ---- scratch layout in d_out (262MB, all dead before LM head writes) ----
    char* ob = (char*)d_out;
    const size_t MB = 1024 * 1024;
    float* x    = (float*)(ob + 0 * MB);    // 8MB   residual [T,D] f32
    u16* fqkv   = (u16*)  (ob + 8 * MB);    // 6MB   [T,1536] qkv packed bf16
    u16* fGU    = (u16*)  (ob + 16 * MB);   // 22MB  [T,5632] gate|up packed bf16
    u16* vt     = (u16*)  (ob + 40 * MB);   // 1MB   V^T [256][T]
    u16* qb     = (u16*)  (ob + 42 * MB);   // 4MB
    u16* kb     = (u16*)  (ob + 47 * MB);   // 1MB
    u16* attnb  = (u16*)  (ob + 48 * MB);   // 4MB
    u16* ffb    = (u16*)  (ob + 52 * MB);   // 11.5MB
    // packed bf16 transposed weights at 64MB+: per-layer region, fixed offsets
    u16* Wt = (u16*)(ob + 64 * MB);
    const size_t OFF_QKV = 0;
    const size_t OFF_O   = (size_t)1536 * 1024;
    const size_t OFF_GU  = OFF_O + (size_t)1024 * 1024;
    const size_t OFF_D   = OFF_GU + (size_t)5632 * 1024;
    const size_t LS      = OFF_D + (size_t)2816 * 1024;   // 11008*1024 elems/layer
    u16* h = (u16*)d_ws;   // 4MB bf16 [T,D]
    bool ws_big = ws_size >= 72 * MB;
    u16* WlmT = ws_big ? (u16*)((char*)d_ws + 4 * MB) : nullptr;  // [NVOCAB][DMODEL]
    (void)in_sizes; (void)n_in; (void)out_size;

    dim3 blk(256);
    // tcast with z = layer axis
    auto tc = [&](const float* in, u16* out, int K, int N, size_t in_ls, int nz) {
        tcast_kernel<<<dim3(N / 32, K / 32, nz), blk, 0, stream>>>(in, out, K, N, in_ls, LS);
    };
    auto gemm_f32 = [&](const u16* A, const u16* BT, float* C, int N, int K, bool add) {
        dim3 g(T_SEQ / 128, N / 128);
        if (add) gemm_bt_kernel<false, true><<<g, blk, 0, stream>>>(A, BT, (void*)C, N, K);
        else     gemm_bt_kernel<false, false><<<g, blk, 0, stream>>>(A, BT, (void*)C, N, K);
    };
    auto gemm_b16 = [&](const u16* A, const u16* BT, u16* C, int N, int K) {
        dim3 g(T_SEQ / 128, N / 128);
        gemm_bt_kernel<true, false><<<g, blk, 0, stream>>>(A, BT, (void*)C, N, K);
    };

    // ---- one-time weight transpose-casts (8 launches, z covers layers) ----
    tc(Wq, Wt + OFF_QKV,                       DMODEL, NH * HEAD_DIM,  (size_t)DMODEL * NH * HEAD_DIM, 2);
    tc(Wk, Wt + OFF_QKV + (size_t)1024 * 1024, DMODEL, NKV * HEAD_DIM, (size_t)DMODEL * NKV * HEAD_DIM, 2);
    tc(Wv, Wt + OFF_QKV + (size_t)1280 * 1024, DMODEL, NKV * HEAD_DIM, (size_t)DMODEL * NKV * HEAD_DIM, 2);
    tc(Wo, Wt + OFF_O,                         DMODEL, DMODEL,         (size_t)DMODEL * DMODEL, 2);
    tc(Wg, Wt + OFF_GU,                        DMODEL, FFDIM,          (size_t)DMODEL * FFDIM, 2);
    tc(Wu, Wt + OFF_GU + (size_t)FFDIM * 1024, DMODEL, FFDIM,          (size_t)DMODEL * FFDIM, 2);
    tc(Wd, Wt + OFF_D,                         FFDIM,  DMODEL,         (size_t)FFDIM * DMODEL, 2);
    if (WlmT)
        tcast_kernel<<<dim3(NVOCAB / 32, DMODEL / 32, 1), blk, 0, stream>>>(
            Wlm, WlmT, DMODEL, NVOCAB, 0, 0);

    // embed + layer-0 rmsnorm fused
    embed_rms_kernel<<<dim3(T_SEQ), blk, 0, stream>>>(toks, emb, ln1, x, h);

    for (int l = 0; l < 2; l++) {
        const u16* WqkvT = Wt + (size_t)l * LS + OFF_QKV;
        const u16* WoT   = Wt + (size_t)l * LS + OFF_O;
        const u16* WguT  = Wt + (size_t)l * LS + OFF_GU;
        const u16* WdT   = Wt + (size_t)l * LS + OFF_D;

        // attn block (h already holds rmsnorm(x, ln1[l]))
        if (l > 0)
            rmsnorm_kernel<<<dim3(T_SEQ), blk, 0, stream>>>(x, ln1 + (size_t)l * DMODEL, h);
        gemm_b16(h, WqkvT, fqkv, 1536, DMODEL);
        ropeall_kernel<<<dim3(5632), blk, 0, stream>>>(fqkv, qb, kb, vt);
        fattn_kernel<<<dim3(T_SEQ / QBLK, NH), blk, 0, stream>>>(qb, kb, vt, attnb);
        gemm_f32(attnb, WoT, x, DMODEL, DMODEL, true);   // fused residual add

        // ffn block
        rmsnorm_kernel<<<dim3(T_SEQ), blk, 0, stream>>>(x, ln2 + (size_t)l * DMODEL, h);
        gemm_b16(h, WguT, fGU, 5632, DMODEL);
        silu_mul_kernel<<<dim3(T_SEQ, FFDIM / 256), blk, 0, stream>>>(fGU, ffb);
        gemm_f32(ffb, WdT, x, DMODEL, FFDIM, true);      // fused residual add
    }

    // final norm + lm head (256x256 3-buffer pipelined kernel, 96KB dynamic LDS)
    rmsnorm_kernel<<<dim3(T_SEQ), blk, 0, stream>>>(x, nw, h);
    if (WlmT) {
        (void)hipFuncSetAttribute(reinterpret_cast<const void*>(gemm256_kernel),
                                  hipFuncAttributeMaxDynamicSharedMemorySize, 98304);
        dim3 g(T_SEQ / 256, NVOCAB / 256);
        gemm256_kernel<<<g, dim3(512), 98304, stream>>>(h, WlmT, (float*)d_out,
                                                        NVOCAB, DMODEL);
    } else {
        dim3 g(NVOCAB / 128, T_SEQ / 128);
        gemm_f32b_kernel<<<g, blk, 0, stream>>>(h, Wlm, (float*)d_out, NVOCAB, DMODEL);
    }
}

// Round 15
// 799.788 us; speedup vs baseline: 1.1102x; 1.0157x over previous
//
#include <hip/hip_runtime.h>

// ---------------- constants ----------------
#define T_SEQ 2048
#define DMODEL 1024
#define NH 16
#define NKV 4
#define HEAD_DIM 64
#define FFDIM 2816
#define NVOCAB 32000

// flash-attn tile params
#define QBLK 64
#define KBLK 128
#define KSS 72
#define VTS 136
#define PSS 136

using u16 = unsigned short;
typedef __bf16 bf16x8 __attribute__((ext_vector_type(8)));
typedef float f32x4 __attribute__((ext_vector_type(4)));

__device__ __forceinline__ float b2f(u16 u) {
    union { unsigned int i; float f; } v; v.i = ((unsigned int)u) << 16; return v.f;
}
__device__ __forceinline__ u16 f2b(float f) {
    unsigned int u = __builtin_bit_cast(unsigned int, f);
    unsigned int r = (u + 0x7FFFu + ((u >> 16) & 1u)) >> 16;
    return (u16)r;
}
// async global->LDS, 16B per lane; LDS dest = wave-uniform base + lane*16
__device__ __forceinline__ void gload16(const u16* g, u16* l) {
    __builtin_amdgcn_global_load_lds(
        (const __attribute__((address_space(1))) void*)g,
        (__attribute__((address_space(3))) void*)l, 16, 0, 0);
}

// ---------------- embed + rmsnorm fused (layer 0): block = row ----------------
__global__ __launch_bounds__(256) void embed_rms_kernel(const int* __restrict__ toks,
                                                        const float* __restrict__ emb,
                                                        const float* __restrict__ w,
                                                        float* __restrict__ x,
                                                        u16* __restrict__ h) {
    __shared__ float red[256];
    const int row = blockIdx.x, tid = threadIdx.x;
    const float* er = emb + (size_t)toks[row] * DMODEL;
    float vals[4]; float ss = 0.f;
#pragma unroll
    for (int i = 0; i < 4; i++) {
        float v = er[tid + 256 * i];
        vals[i] = v; ss += v * v;
        x[(size_t)row * DMODEL + tid + 256 * i] = v;
    }
    red[tid] = ss; __syncthreads();
    for (int s = 128; s > 0; s >>= 1) { if (tid < s) red[tid] += red[tid + s]; __syncthreads(); }
    float inv = rsqrtf(red[0] * (1.0f / DMODEL) + 1e-5f);
#pragma unroll
    for (int i = 0; i < 4; i++) {
        int c = tid + 256 * i;
        h[(size_t)row * DMODEL + c] = f2b(vals[i] * inv * w[c]);
    }
}

// ---------------- rmsnorm: f32 in -> bf16 out ----------------
__global__ __launch_bounds__(256) void rmsnorm_kernel(const float* __restrict__ x,
                                                      const float* __restrict__ w,
                                                      u16* __restrict__ out) {
    __shared__ float red[256];
    const int row = blockIdx.x, tid = threadIdx.x;
    const float* xr = x + (size_t)row * DMODEL;
    float vals[4]; float ss = 0.f;
#pragma unroll
    for (int i = 0; i < 4; i++) { float v = xr[tid + 256 * i]; vals[i] = v; ss += v * v; }
    red[tid] = ss; __syncthreads();
    for (int s = 128; s > 0; s >>= 1) { if (tid < s) red[tid] += red[tid + s]; __syncthreads(); }
    float inv = rsqrtf(red[0] * (1.0f / DMODEL) + 1e-5f);
#pragma unroll
    for (int i = 0; i < 4; i++) {
        int c = tid + 256 * i;
        out[(size_t)row * DMODEL + c] = f2b(vals[i] * inv * w[c]);
    }
}

// ---------------- transpose-cast: in[K][N] f32 -> out[N][K] bf16, z = layer ----------------
__global__ __launch_bounds__(256) void tcast_kernel(const float* __restrict__ in,
                                                    u16* __restrict__ out, int K, int N,
                                                    size_t in_ls, size_t out_ls) {
    __shared__ float tile[32][33];
    in += (size_t)blockIdx.z * in_ls;
    out += (size_t)blockIdx.z * out_ls;
    int bx = blockIdx.x * 32;  // N
    int by = blockIdx.y * 32;  // K
    int tx = threadIdx.x & 31, ty = threadIdx.x >> 5;
#pragma unroll
    for (int i = 0; i < 32; i += 8)
        tile[ty + i][tx] = in[(size_t)(by + ty + i) * N + bx + tx];
    __syncthreads();
#pragma unroll
    for (int i = 0; i < 32; i += 8)
        out[(size_t)(bx + ty + i) * K + by + tx] = f2b(tile[tx][ty + i]);
}

// ---------------- gate/up interleaved transpose-cast ----------------
// packed[32q+r][k] = r<16 ? Wg[k][16q+r] : Wu[k][16q+r-16]
__global__ __launch_bounds__(256) void tcast_gu_kernel(const float* __restrict__ Wg,
                                                       const float* __restrict__ Wu,
                                                       u16* __restrict__ out,
                                                       size_t w_ls, size_t out_ls) {
    __shared__ float tg[32][17], tu[32][17];
    Wg += (size_t)blockIdx.z * w_ls;
    Wu += (size_t)blockIdx.z * w_ls;
    out += (size_t)blockIdx.z * out_ls;
    const int Q = blockIdx.x;            // 16-col gate/up group (0..175)
    const int KY = blockIdx.y * 32;      // k tile
    const int tid = threadIdx.x;
    const int tx = tid & 15, ty = tid >> 4;   // 16 cols x 16 k-rows
#pragma unroll
    for (int i = 0; i < 32; i += 16) {
        tg[ty + i][tx] = Wg[(size_t)(KY + ty + i) * FFDIM + Q * 16 + tx];
        tu[ty + i][tx] = Wu[(size_t)(KY + ty + i) * FFDIM + Q * 16 + tx];
    }
    __syncthreads();
    const int tx2 = tid & 31, ty2 = tid >> 5;   // 32 k x 8 r per pass
#pragma unroll
    for (int i = 0; i < 32; i += 8) {
        int r = ty2 + i;
        float v = (r < 16) ? tg[tx2][r] : tu[tx2][r - 16];
        out[(size_t)(Q * 32 + r) * DMODEL + KY + tx2] = f2b(v);
    }
}

// ---------------- rope cos/sin table: tbl[t*32+i] = {cos,sin}(t * theta^-i/32) ----------------
__global__ __launch_bounds__(256) void rope_table_kernel(float2* __restrict__ tbl) {
    int idx = blockIdx.x * 256 + threadIdx.x;   // < 2048*32
    int t = idx >> 5, i = idx & 31;
    float inv = expf(-(float)i * (9.210340371976184f / 32.0f));
    float ang = (float)t * inv;
    tbl[idx] = make_float2(cosf(ang), sinf(ang));
}

// ---------------- fused rope(q) + rope(k) + V-transpose (table-driven) ----------------
__global__ __launch_bounds__(256) void ropeall_kernel(const u16* __restrict__ fqkv,
                                                      const float2* __restrict__ tbl,
                                                      u16* __restrict__ qb,
                                                      u16* __restrict__ kb,
                                                      u16* __restrict__ vt) {
    __shared__ u16 tile[32][33];
    const int bid = blockIdx.x, tid = threadIdx.x;
    if (bid < 5120) {
        int i, t, hh, coloff;
        u16* out;
        size_t rest;
        if (bid < 4096) {   // q: heads=16
            int idx = bid * 256 + tid;
            i = idx & 31; rest = idx >> 5;
            t = (int)(rest >> 4); hh = (int)(rest & 15); coloff = 0; out = qb;
        } else {            // k: heads=4
            int idx = (bid - 4096) * 256 + tid;
            i = idx & 31; rest = idx >> 5;
            t = (int)(rest >> 2); hh = (int)(rest & 3); coloff = 1024; out = kb;
        }
        float2 cs = tbl[t * 32 + i];
        size_t src = (size_t)t * 1536 + coloff + hh * HEAD_DIM + 2 * i;
        size_t dst = rest * HEAD_DIM + 2 * i;
        float x0 = b2f(fqkv[src]), x1 = b2f(fqkv[src + 1]);
        out[dst]     = f2b(x0 * cs.x - x1 * cs.y);
        out[dst + 1] = f2b(x0 * cs.y + x1 * cs.x);
    } else {
        // V transpose: fqkv[:,1280:1536] -> vt[256][T]
        int b2 = bid - 5120;
        int bx = (b2 & 7) * 32;    // v-dim
        int by = (b2 >> 3) * 32;   // t
        int tx = tid & 31, ty = tid >> 5;
#pragma unroll
        for (int i = 0; i < 32; i += 8)
            tile[ty + i][tx] = fqkv[(size_t)(by + ty + i) * 1536 + 1280 + bx + tx];
        __syncthreads();
#pragma unroll
        for (int i = 0; i < 32; i += 8)
            vt[(size_t)(bx + ty + i) * T_SEQ + by + tx] = tile[tx][ty + i];
    }
}

// ---------------- GEMM-BT 128x128 (2-phase, proven): C = A * BT^T ----------------
template<bool OUT_BF16, bool ADD>
__global__ __launch_bounds__(256) void gemm_bt_kernel(const u16* __restrict__ A,
                                                      const u16* __restrict__ BT,
                                                      void* __restrict__ Cp,
                                                      int N, int K) {
    __shared__ __align__(16) u16 As[2][128 * 32];
    __shared__ __align__(16) u16 Bs[2][128 * 32];
    const int tid = threadIdx.x;
    const int gx = gridDim.x;
    const int nwg = gx * gridDim.y;
    const int hwid = blockIdx.y * gx + blockIdx.x;
    const int q = nwg >> 3, r = nwg & 7;
    const int xcd = hwid & 7, rem = hwid >> 3;
    const int wgid = (xcd < r ? xcd * (q + 1) : r * (q + 1) + (xcd - r) * q) + rem;
    const int brow = wgid % gx, bcol = wgid / gx;

    const int w = tid >> 6, lane = tid & 63;
    const int wr = w >> 1, wc = w & 1;
    const int lg = lane >> 4, lr = lane & 15;

    f32x4 acc[4][4] = {};

    const int srow = w * 32 + (lane >> 2);
    const int scol = (lane & 3) << 3;
    const u16* gA = A + (size_t)(brow * 128 + srow) * K + scol;
    const u16* gB = BT + (size_t)(bcol * 128 + srow) * K + scol;
    const size_t koff16 = (size_t)16 * K;
    const int lofs0 = (w * 32) * 32;
    const int lofs1 = (w * 32 + 16) * 32;

    const int nt = K >> 5;
    gload16(gA, &As[0][lofs0]);
    gload16(gA + koff16, &As[0][lofs1]);
    gload16(gB, &Bs[0][lofs0]);
    gload16(gB + koff16, &Bs[0][lofs1]);
    __syncthreads();

    int cur = 0;
    for (int t = 0; t < nt; t++) {
        if (t + 1 < nt) {
            const int kb = (t + 1) << 5;
            gload16(gA + kb, &As[cur ^ 1][lofs0]);
            gload16(gA + koff16 + kb, &As[cur ^ 1][lofs1]);
            gload16(gB + kb, &Bs[cur ^ 1][lofs0]);
            gload16(gB + koff16 + kb, &Bs[cur ^ 1][lofs1]);
        }
        bf16x8 aF[4], bF[4];
#pragma unroll
        for (int m = 0; m < 4; m++)
            aF[m] = *(const bf16x8*)(&As[cur][(wr * 64 + m * 16 + lr) * 32 + lg * 8]);
#pragma unroll
        for (int n = 0; n < 4; n++)
            bF[n] = *(const bf16x8*)(&Bs[cur][(wc * 64 + n * 16 + lr) * 32 + lg * 8]);
#pragma unroll
        for (int m = 0; m < 4; m++)
#pragma unroll
            for (int n = 0; n < 4; n++)
                acc[m][n] = __builtin_amdgcn_mfma_f32_16x16x32_bf16(aF[m], bF[n], acc[m][n], 0, 0, 0);
        __syncthreads();
        cur ^= 1;
    }

#pragma unroll
    for (int m = 0; m < 4; m++)
#pragma unroll
        for (int n = 0; n < 4; n++)
#pragma unroll
            for (int j = 0; j < 4; j++) {
                int row = brow * 128 + wr * 64 + m * 16 + lg * 4 + j;
                int col = bcol * 128 + wc * 64 + n * 16 + lr;
                size_t idx = (size_t)row * N + col;
                float v = acc[m][n][j];
                if constexpr (OUT_BF16) {
                    ((u16*)Cp)[idx] = f2b(v);
                } else if constexpr (ADD) {
                    ((float*)Cp)[idx] = ((const float*)Cp)[idx] + v;
                } else {
                    ((float*)Cp)[idx] = v;
                }
            }
}

// ---------------- GEMM-BT 256x256, 3-buffer pipelined ----------------
// MODE 0: f32 C[M][Nout]. MODE 3: fused silu-pair: BT is gate/up interleaved
// (packed col 32q+r: r<16 gate, r>=16 up); writes bf16 out[M][Nout=N/2] with
// out[row][bC*128+wn*32+(n/2)*16+lr] = silu(acc[n]) * acc[n+1], n in {0,2}.
template<int MODE>
__global__ __launch_bounds__(512) void gemm256_kernel(const u16* __restrict__ A,
                                                      const u16* __restrict__ BT,
                                                      void* __restrict__ Cp,
                                                      int Nout, int K) {
    extern __shared__ __align__(16) u16 lds[];
    const int tid = threadIdx.x;
    const int gx = gridDim.x;
    const int nwg = gx * gridDim.y;
    const int hwid = blockIdx.y * gx + blockIdx.x;
    const int q = nwg >> 3, r = nwg & 7;
    const int xcd = hwid & 7, rem = hwid >> 3;
    const int wgid = (xcd < r ? xcd * (q + 1) : r * (q + 1) + (xcd - r) * q) + rem;
    const int bR = wgid % gx, bC = wgid / gx;

    const int w = tid >> 6, lane = tid & 63;
    const int wm = w >> 2, wn = w & 3;
    const int lg = lane >> 4, lr = lane & 15;

    f32x4 acc[8][4] = {};

    const int srow = lane >> 2;                                    // row in band
    const int scol = ((lane & 3) ^ ((lane >= 32) ? 2 : 0)) << 3;   // swizzled src col
    const int rblk = (((lr >= 8) ? (lg ^ 2) : lg)) << 4;           // ds_read byte blk

    const u16* Ab = A + (size_t)(bR * 256) * K + scol;
    const u16* Bb = BT + (size_t)(bC * 256) * K + scol;

    auto STAGE_A = [&](int t, int b) {
        gload16(Ab + (size_t)(w * 16 + srow) * K + t * 32,
                lds + (b * 16384 + w * 1024) / 2);
        gload16(Ab + (size_t)((w + 8) * 16 + srow) * K + t * 32,
                lds + (b * 16384 + (w + 8) * 1024) / 2);
    };
    auto STAGE_B = [&](int t, int b) {
        gload16(Bb + (size_t)(w * 16 + srow) * K + t * 32,
                lds + (49152 + b * 16384 + w * 1024) / 2);
        gload16(Bb + (size_t)((w + 8) * 16 + srow) * K + t * 32,
                lds + (49152 + b * 16384 + (w + 8) * 1024) / 2);
    };

    const int nt = K >> 5;
    STAGE_A(0, 0); STAGE_B(0, 0);
    STAGE_A(1, 1); STAGE_B(1, 1);
    asm volatile("s_waitcnt vmcnt(4)" ::: "memory");
    __builtin_amdgcn_s_barrier();

    int cur = 0;
    for (int t = 0; t < nt; t++) {
        const bool st = (t + 2 < nt);
        const int nb = (cur >= 1) ? cur - 1 : cur + 2;   // (cur+2)%3
        bf16x8 bF[4];
        // ---- phase 0: m-frags 0-3 (reads bF for the whole tile) ----
        {
            bf16x8 aF[4];
#pragma unroll
            for (int mi = 0; mi < 4; mi++)
                aF[mi] = *(const bf16x8*)((const char*)lds + cur * 16384 +
                                          (wm * 8 + mi) * 1024 + lr * 64 + rblk);
#pragma unroll
            for (int n = 0; n < 4; n++)
                bF[n] = *(const bf16x8*)((const char*)lds + 49152 + cur * 16384 +
                                         (wn * 4 + n) * 1024 + lr * 64 + rblk);
            if (st) STAGE_A(t + 2, nb);
            __builtin_amdgcn_s_barrier();
            asm volatile("s_waitcnt lgkmcnt(0)" ::: "memory");
            __builtin_amdgcn_sched_barrier(0);
            __builtin_amdgcn_s_setprio(1);
#pragma unroll
            for (int mi = 0; mi < 4; mi++)
#pragma unroll
                for (int n = 0; n < 4; n++)
                    acc[mi][n] = __builtin_amdgcn_mfma_f32_16x16x32_bf16(
                        aF[mi], bF[n], acc[mi][n], 0, 0, 0);
            __builtin_amdgcn_s_setprio(0);
            __builtin_amdgcn_s_barrier();
        }
        // ---- phase 1: m-frags 4-7 (reuses bF registers) ----
        {
            bf16x8 aF[4];
#pragma unroll
            for (int mi = 0; mi < 4; mi++)
                aF[mi] = *(const bf16x8*)((const char*)lds + cur * 16384 +
                                          (wm * 8 + 4 + mi) * 1024 + lr * 64 + rblk);
            if (st) STAGE_B(t + 2, nb);
            if (t + 1 < nt) {
                if (st) asm volatile("s_waitcnt vmcnt(4)" ::: "memory");
                else    asm volatile("s_waitcnt vmcnt(0)" ::: "memory");
            }
            __builtin_amdgcn_s_barrier();
            asm volatile("s_waitcnt lgkmcnt(0)" ::: "memory");
            __builtin_amdgcn_sched_barrier(0);
            __builtin_amdgcn_s_setprio(1);
#pragma unroll
            for (int mi = 0; mi < 4; mi++)
#pragma unroll
                for (int n = 0; n < 4; n++)
                    acc[4 + mi][n] = __builtin_amdgcn_mfma_f32_16x16x32_bf16(
                        aF[mi], bF[n], acc[4 + mi][n], 0, 0, 0);
            __builtin_amdgcn_s_setprio(0);
            __builtin_amdgcn_s_barrier();
        }
        cur = (cur == 2) ? 0 : cur + 1;
    }

#pragma unroll
    for (int m = 0; m < 8; m++) {
        if constexpr (MODE == 0) {
#pragma unroll
            for (int n = 0; n < 4; n++)
#pragma unroll
                for (int jj = 0; jj < 4; jj++) {
                    int row = bR * 256 + wm * 128 + m * 16 + lg * 4 + jj;
                    int col = bC * 256 + wn * 64 + n * 16 + lr;
                    ((float*)Cp)[(size_t)row * Nout + col] = acc[m][n][jj];
                }
        } else {
#pragma unroll
            for (int n = 0; n < 4; n += 2)
#pragma unroll
                for (int jj = 0; jj < 4; jj++) {
                    int row = bR * 256 + wm * 128 + m * 16 + lg * 4 + jj;
                    int col = bC * 128 + wn * 32 + (n >> 1) * 16 + lr;
                    float g = acc[m][n][jj], u = acc[m][n + 1][jj];
                    float s = g / (1.f + __expf(-g));
                    ((u16*)Cp)[(size_t)row * Nout + col] = f2b(s * u);
                }
        }
    }
}

// ---------------- fallback GEMM (f32 B, non-transposed) — LM head only ----------------
__device__ __forceinline__ int bs_off(int c, int k) {
    return c * 40 + ((((k >> 3) ^ ((c >> 3) & 3)) << 3) | (k & 7));
}

__global__ __launch_bounds__(256) void gemm_f32b_kernel(const u16* __restrict__ A,
                                                        const float* __restrict__ B,
                                                        float* __restrict__ C,
                                                        int N, int K) {
    __shared__ __align__(16) u16 As[128 * 40];
    __shared__ __align__(16) u16 Bs[128 * 40];
    const int tid = threadIdx.x;
    const int brow = blockIdx.y, bcol = blockIdx.x;
    const int wid = tid >> 6, lane = tid & 63;
    const int wr = wid >> 1, wc = wid & 1;
    const int lg = lane >> 4, lr = lane & 15;

    f32x4 acc[4][4] = {};
    const int ar = tid >> 2, ac = (tid & 3) << 3;
    const int bk = tid >> 4, bc = (tid & 15) << 3;

    for (int kb = 0; kb < K; kb += 32) {
        {
            const u16* ga = A + (size_t)(brow * 128 + ar) * K + kb + ac;
            *(uint4*)(&As[ar * 40 + ac]) = *(const uint4*)ga;
            *(uint4*)(&As[(ar + 64) * 40 + ac]) = *(const uint4*)(ga + (size_t)64 * K);
        }
        {
            const float* gb = B + (size_t)(kb + bk) * N + bcol * 128 + bc;
            float4 a0 = *(const float4*)gb;
            float4 a1 = *(const float4*)(gb + 4);
            float4 b0 = *(const float4*)(gb + (size_t)16 * N);
            float4 b1 = *(const float4*)(gb + (size_t)16 * N + 4);
            float f0[8] = {a0.x, a0.y, a0.z, a0.w, a1.x, a1.y, a1.z, a1.w};
            float f1[8] = {b0.x, b0.y, b0.z, b0.w, b1.x, b1.y, b1.z, b1.w};
#pragma unroll
            for (int i = 0; i < 8; i++) {
                Bs[bs_off(bc + i, bk)] = f2b(f0[i]);
                Bs[bs_off(bc + i, bk + 16)] = f2b(f1[i]);
            }
        }
        __syncthreads();

        bf16x8 aF[4], bF[4];
#pragma unroll
        for (int m = 0; m < 4; m++)
            aF[m] = *(const bf16x8*)(&As[(wr * 64 + m * 16 + lr) * 40 + lg * 8]);
#pragma unroll
        for (int n = 0; n < 4; n++) {
            int c = wc * 64 + n * 16 + lr;
            bF[n] = *(const bf16x8*)(&Bs[c * 40 + ((lg ^ ((c >> 3) & 3)) << 3)]);
        }
#pragma unroll
        for (int m = 0; m < 4; m++)
#pragma unroll
            for (int n = 0; n < 4; n++)
                acc[m][n] = __builtin_amdgcn_mfma_f32_16x16x32_bf16(aF[m], bF[n], acc[m][n], 0, 0, 0);
        __syncthreads();
    }

#pragma unroll
    for (int m = 0; m < 4; m++)
#pragma unroll
        for (int n = 0; n < 4; n++)
#pragma unroll
            for (int j = 0; j < 4; j++) {
                int row = brow * 128 + wr * 64 + m * 16 + lg * 4 + j;
                int col = bcol * 128 + wc * 64 + n * 16 + lr;
                C[(size_t)row * N + col] = acc[m][n][j];
            }
}

// ---------------- flash attention ----------------
__global__ __launch_bounds__(256) void fattn_kernel(const u16* __restrict__ q,
                                                    const u16* __restrict__ k,
                                                    const u16* __restrict__ vt,
                                                    u16* __restrict__ out) {
    __shared__ __align__(16) u16 Ks[KBLK * KSS];
    __shared__ __align__(16) u16 Vt[HEAD_DIM * VTS];
    __shared__ __align__(16) u16 Ps[QBLK * PSS];
    const int tid = threadIdx.x;
    const int qb0 = blockIdx.x * QBLK, h = blockIdx.y, kvh = h >> 2;
    const int w = tid >> 6, lane = tid & 63;
    const int lg = lane >> 4, lr = lane & 15;

    bf16x8 qf0, qf1;
    {
        const u16* src = q + ((size_t)(qb0 + w * 16 + lr) * NH + h) * HEAD_DIM;
        qf0 = *(const bf16x8*)(src + lg * 8);
        qf1 = *(const bf16x8*)(src + 32 + lg * 8);
    }

    f32x4 acc_o[4] = {};
    float m_run[4] = {-1e30f, -1e30f, -1e30f, -1e30f};
    float l_run[4] = {0.f, 0.f, 0.f, 0.f};

    const int ntiles = (qb0 + QBLK - 1) / KBLK + 1;

    for (int kt = 0; kt < ntiles; kt++) {
        const int kb = kt * KBLK;
        __syncthreads();
        for (int c = tid; c < KBLK * 8; c += 256) {
            int row = c >> 3, c8 = (c & 7) << 3;
            *(uint4*)(&Ks[row * KSS + c8]) =
                *(const uint4*)(k + ((size_t)(kb + row) * NKV + kvh) * HEAD_DIM + c8);
        }
        for (int c = tid; c < HEAD_DIM * 16; c += 256) {
            int d = c >> 4, c16 = (c & 15) << 3;
            *(uint4*)(&Vt[d * VTS + c16]) =
                *(const uint4*)(vt + (size_t)(kvh * HEAD_DIM + d) * T_SEQ + kb + c16);
        }
        __syncthreads();

        f32x4 s[8] = {};
#pragma unroll
        for (int n = 0; n < 8; n++) {
            bf16x8 kf0 = *(const bf16x8*)(&Ks[(n * 16 + lr) * KSS + lg * 8]);
            bf16x8 kf1 = *(const bf16x8*)(&Ks[(n * 16 + lr) * KSS + 32 + lg * 8]);
            s[n] = __builtin_amdgcn_mfma_f32_16x16x32_bf16(qf0, kf0, s[n], 0, 0, 0);
            s[n] = __builtin_amdgcn_mfma_f32_16x16x32_bf16(qf1, kf1, s[n], 0, 0, 0);
        }

#pragma unroll
        for (int j = 0; j < 4; j++) {
            int q_g = qb0 + w * 16 + lg * 4 + j;
            float sv[8];
            float tmax = -1e30f;
#pragma unroll
            for (int n = 0; n < 8; n++) {
                float xx = s[n][j] * 0.125f;
                if (kb + n * 16 + lr > q_g) xx = -1e30f;
                sv[n] = xx;
                tmax = fmaxf(tmax, xx);
            }
#pragma unroll
            for (int mm = 1; mm < 16; mm <<= 1) tmax = fmaxf(tmax, __shfl_xor(tmax, mm));
            float mn = fmaxf(m_run[j], tmax);
            float sc = __expf(m_run[j] - mn);
            m_run[j] = mn;
            float rsum = 0.f;
#pragma unroll
            for (int n = 0; n < 8; n++) {
                float p = __expf(sv[n] - mn);
                rsum += p;
                Ps[(w * 16 + lg * 4 + j) * PSS + n * 16 + lr] = f2b(p);
            }
#pragma unroll
            for (int mm = 1; mm < 16; mm <<= 1) rsum += __shfl_xor(rsum, mm);
            l_run[j] = l_run[j] * sc + rsum;
#pragma unroll
            for (int n = 0; n < 4; n++) acc_o[n][j] *= sc;
        }

#pragma unroll
        for (int ks = 0; ks < 4; ks++) {
            bf16x8 pf = *(const bf16x8*)(&Ps[(w * 16 + lr) * PSS + ks * 32 + lg * 8]);
#pragma unroll
            for (int n = 0; n < 4; n++) {
                bf16x8 vf = *(const bf16x8*)(&Vt[(n * 16 + lr) * VTS + ks * 32 + lg * 8]);
                acc_o[n] = __builtin_amdgcn_mfma_f32_16x16x32_bf16(pf, vf, acc_o[n], 0, 0, 0);
            }
        }
    }

#pragma unroll
    for (int n = 0; n < 4; n++)
#pragma unroll
        for (int j = 0; j < 4; j++) {
            int t = qb0 + w * 16 + lg * 4 + j;
            int d = n * 16 + lr;
            out[((size_t)t * NH + h) * HEAD_DIM + d] = f2b(acc_o[n][j] / l_run[j]);
        }
}

// ---------------- host launch ----------------
extern "C" void kernel_launch(void* const* d_in, const int* in_sizes, int n_in,
                              void* d_out, int out_size, void* d_ws, size_t ws_size,
                              hipStream_t stream) {
    const int*   toks = (const int*)d_in[0];
    const float* emb  = (const float*)d_in[1];
    const float* Wq   = (const float*)d_in[2];
    const float* Wk   = (const float*)d_in[3];
    const float* Wv   = (const float*)d_in[4];
    const float* Wo   = (const float*)d_in[5];
    const float* Wg   = (const float*)d_in[6];
    const float* Wu   = (const float*)d_in[7];
    const float* Wd   = (const float*)d_in[8];
    const float* ln1  = (const float*)d_in[9];
    const float* ln2  = (const float*)d_in[10];
    const float* nw   = (const float*)d_in[11];
    const float* Wlm  = (const float*)d_in[12];

    // ---- scratch layout in d_out (262MB, all dead before LM head writes) ----
    char* ob = (char*)d_out;
    const size_t MB = 1024 * 1024;
    float* x    = (float*)(ob + 0 * MB);    // 8MB   residual [T,D] f32
    u16* fqkv   = (u16*)  (ob + 8 * MB);    // 6MB   [T,1536] qkv packed bf16
    float2* tbl = (float2*)(ob + 16 * MB);  // 512KB rope table
    u16* vt     = (u16*)  (ob + 40 * MB);   // 1MB   V^T [256][T]
    u16* qb     = (u16*)  (ob + 42 * MB);   // 4MB
    u16* kb     = (u16*)  (ob + 47 * MB);   // 1MB
    u16* attnb  = (u16*)  (ob + 48 * MB);   // 4MB
    u16* ffb    = (u16*)  (ob + 52 * MB);   // 11.5MB
    // packed bf16 transposed weights at 64MB+: per-layer region, fixed offsets
    u16* Wt = (u16*)(ob + 64 * MB);
    const size_t OFF_QKV = 0;
    const size_t OFF_O   = (size_t)1536 * 1024;
    const size_t OFF_GU  = OFF_O + (size_t)1024 * 1024;      // gate/up interleaved [5632][1024]
    const size_t OFF_D   = OFF_GU + (size_t)5632 * 1024;
    const size_t LS      = OFF_D + (size_t)2816 * 1024;      // elems/layer
    u16* h = (u16*)d_ws;   // 4MB bf16 [T,D]
    bool ws_big = ws_size >= 72 * MB;
    u16* WlmT = ws_big ? (u16*)((char*)d_ws + 4 * MB) : nullptr;  // [NVOCAB][DMODEL]
    (void)in_sizes; (void)n_in; (void)out_size;

    dim3 blk(256);
    auto tc = [&](const float* in, u16* out, int K, int N, size_t in_ls, int nz) {
        tcast_kernel<<<dim3(N / 32, K / 32, nz), blk, 0, stream>>>(in, out, K, N, in_ls, LS);
    };
    auto gemm_f32 = [&](const u16* A, const u16* BT, float* C, int N, int K, bool add) {
        dim3 g(T_SEQ / 128, N / 128);
        if (add) gemm_bt_kernel<false, true><<<g, blk, 0, stream>>>(A, BT, (void*)C, N, K);
        else     gemm_bt_kernel<false, false><<<g, blk, 0, stream>>>(A, BT, (void*)C, N, K);
    };
    auto gemm_b16 = [&](const u16* A, const u16* BT, u16* C, int N, int K) {
        dim3 g(T_SEQ / 128, N / 128);
        gemm_bt_kernel<true, false><<<g, blk, 0, stream>>>(A, BT, (void*)C, N, K);
    };

    // ---- one-time weight transpose-casts ----
    tc(Wq, Wt + OFF_QKV,                       DMODEL, NH * HEAD_DIM,  (size_t)DMODEL * NH * HEAD_DIM, 2);
    tc(Wk, Wt + OFF_QKV + (size_t)1024 * 1024, DMODEL, NKV * HEAD_DIM, (size_t)DMODEL * NKV * HEAD_DIM, 2);
    tc(Wv, Wt + OFF_QKV + (size_t)1280 * 1024, DMODEL, NKV * HEAD_DIM, (size_t)DMODEL * NKV * HEAD_DIM, 2);
    tc(Wo, Wt + OFF_O,                         DMODEL, DMODEL,         (size_t)DMODEL * DMODEL, 2);
    tcast_gu_kernel<<<dim3(FFDIM / 16, DMODEL / 32, 2), blk, 0, stream>>>(
        Wg, Wu, Wt + OFF_GU, (size_t)DMODEL * FFDIM, LS);
    tc(Wd, Wt + OFF_D,                         FFDIM,  DMODEL,         (size_t)FFDIM * DMODEL, 2);
    if (WlmT)
        tcast_kernel<<<dim3(NVOCAB / 32, DMODEL / 32, 1), blk, 0, stream>>>(
            Wlm, WlmT, DMODEL, NVOCAB, 0, 0);
    rope_table_kernel<<<dim3(T_SEQ * 32 / 256), blk, 0, stream>>>(tbl);

    // set dynamic-LDS attribute for both gemm256 instantiations
    (void)hipFuncSetAttribute(reinterpret_cast<const void*>(gemm256_kernel<0>),
                              hipFuncAttributeMaxDynamicSharedMemorySize, 98304);
    (void)hipFuncSetAttribute(reinterpret_cast<const void*>(gemm256_kernel<3>),
                              hipFuncAttributeMaxDynamicSharedMemorySize, 98304);

    // embed + layer-0 rmsnorm fused
    embed_rms_kernel<<<dim3(T_SEQ), blk, 0, stream>>>(toks, emb, ln1, x, h);

    for (int l = 0; l < 2; l++) {
        const u16* WqkvT = Wt + (size_t)l * LS + OFF_QKV;
        const u16* WoT   = Wt + (size_t)l * LS + OFF_O;
        const u16* WguT  = Wt + (size_t)l * LS + OFF_GU;
        const u16* WdT   = Wt + (size_t)l * LS + OFF_D;

        // attn block (h already holds rmsnorm(x, ln1[l]))
        if (l > 0)
            rmsnorm_kernel<<<dim3(T_SEQ), blk, 0, stream>>>(x, ln1 + (size_t)l * DMODEL, h);
        gemm_b16(h, WqkvT, fqkv, 1536, DMODEL);
        ropeall_kernel<<<dim3(5632), blk, 0, stream>>>(fqkv, tbl, qb, kb, vt);
        fattn_kernel<<<dim3(T_SEQ / QBLK, NH), blk, 0, stream>>>(qb, kb, vt, attnb);
        gemm_f32(attnb, WoT, x, DMODEL, DMODEL, true);   // fused residual add

        // ffn block: GU gemm256 with fused silu -> ffb (bf16), then down-proj
        rmsnorm_kernel<<<dim3(T_SEQ), blk, 0, stream>>>(x, ln2 + (size_t)l * DMODEL, h);
        {
            dim3 g(T_SEQ / 256, 5632 / 256);   // 8 x 22 = 176 blocks, %8 == 0
            gemm256_kernel<3><<<g, dim3(512), 98304, stream>>>(h, WguT, (void*)ffb,
                                                               FFDIM, DMODEL);
        }
        gemm_f32(ffb, WdT, x, DMODEL, FFDIM, true);      // fused residual add
    }

    // final norm + lm head (256x256 3-buffer pipelined kernel, 96KB dynamic LDS)
    rmsnorm_kernel<<<dim3(T_SEQ), blk, 0, stream>>>(x, nw, h);
    if (WlmT) {
        dim3 g(T_SEQ / 256, NVOCAB / 256);
        gemm256_kernel<0><<<g, dim3(512), 98304, stream>>>(h, WlmT, (void*)d_out,
                                                           NVOCAB, DMODEL);
    } else {
        dim3 g(NVOCAB / 128, T_SEQ / 128);
        gemm_f32b_kernel<<<g, blk, 0, stream>>>(h, Wlm, (float*)d_out, NVOCAB, DMODEL);
    }
}

// Round 16
// 766.011 us; speedup vs baseline: 1.1591x; 1.0441x over previous
//
#include <hip/hip_runtime.h>

// ---------------- constants ----------------
#define T_SEQ 2048
#define DMODEL 1024
#define NH 16
#define NKV 4
#define HEAD_DIM 64
#define FFDIM 2816
#define NVOCAB 32000

// flash-attn tile params
#define QBLK 128
#define KBLK 128
#define KSS 72
#define VTS 136
#define PSS 136

using u16 = unsigned short;
typedef __bf16 bf16x8 __attribute__((ext_vector_type(8)));
typedef float f32x4 __attribute__((ext_vector_type(4)));

__device__ __forceinline__ float b2f(u16 u) {
    union { unsigned int i; float f; } v; v.i = ((unsigned int)u) << 16; return v.f;
}
__device__ __forceinline__ u16 f2b(float f) {
    unsigned int u = __builtin_bit_cast(unsigned int, f);
    unsigned int r = (u + 0x7FFFu + ((u >> 16) & 1u)) >> 16;
    return (u16)r;
}
// async global->LDS, 16B per lane; LDS dest = wave-uniform base + lane*16
__device__ __forceinline__ void gload16(const u16* g, u16* l) {
    __builtin_amdgcn_global_load_lds(
        (const __attribute__((address_space(1))) void*)g,
        (__attribute__((address_space(3))) void*)l, 16, 0, 0);
}

// ---------------- embed + rmsnorm fused (layer 0): block = row ----------------
__global__ __launch_bounds__(256) void embed_rms_kernel(const int* __restrict__ toks,
                                                        const float* __restrict__ emb,
                                                        const float* __restrict__ w,
                                                        float* __restrict__ x,
                                                        u16* __restrict__ h) {
    __shared__ float red[256];
    const int row = blockIdx.x, tid = threadIdx.x;
    const float* er = emb + (size_t)toks[row] * DMODEL;
    float vals[4]; float ss = 0.f;
#pragma unroll
    for (int i = 0; i < 4; i++) {
        float v = er[tid + 256 * i];
        vals[i] = v; ss += v * v;
        x[(size_t)row * DMODEL + tid + 256 * i] = v;
    }
    red[tid] = ss; __syncthreads();
    for (int s = 128; s > 0; s >>= 1) { if (tid < s) red[tid] += red[tid + s]; __syncthreads(); }
    float inv = rsqrtf(red[0] * (1.0f / DMODEL) + 1e-5f);
#pragma unroll
    for (int i = 0; i < 4; i++) {
        int c = tid + 256 * i;
        h[(size_t)row * DMODEL + c] = f2b(vals[i] * inv * w[c]);
    }
}

// ---------------- rmsnorm: f32 in -> bf16 out ----------------
__global__ __launch_bounds__(256) void rmsnorm_kernel(const float* __restrict__ x,
                                                      const float* __restrict__ w,
                                                      u16* __restrict__ out) {
    __shared__ float red[256];
    const int row = blockIdx.x, tid = threadIdx.x;
    const float* xr = x + (size_t)row * DMODEL;
    float vals[4]; float ss = 0.f;
#pragma unroll
    for (int i = 0; i < 4; i++) { float v = xr[tid + 256 * i]; vals[i] = v; ss += v * v; }
    red[tid] = ss; __syncthreads();
    for (int s = 128; s > 0; s >>= 1) { if (tid < s) red[tid] += red[tid + s]; __syncthreads(); }
    float inv = rsqrtf(red[0] * (1.0f / DMODEL) + 1e-5f);
#pragma unroll
    for (int i = 0; i < 4; i++) {
        int c = tid + 256 * i;
        out[(size_t)row * DMODEL + c] = f2b(vals[i] * inv * w[c]);
    }
}

// ---------------- transpose-cast: in[K][N] f32 -> out[N][K] bf16, z = layer ----------------
__global__ __launch_bounds__(256) void tcast_kernel(const float* __restrict__ in,
                                                    u16* __restrict__ out, int K, int N,
                                                    size_t in_ls, size_t out_ls) {
    __shared__ float tile[32][33];
    in += (size_t)blockIdx.z * in_ls;
    out += (size_t)blockIdx.z * out_ls;
    int bx = blockIdx.x * 32;  // N
    int by = blockIdx.y * 32;  // K
    int tx = threadIdx.x & 31, ty = threadIdx.x >> 5;
#pragma unroll
    for (int i = 0; i < 32; i += 8)
        tile[ty + i][tx] = in[(size_t)(by + ty + i) * N + bx + tx];
    __syncthreads();
#pragma unroll
    for (int i = 0; i < 32; i += 8)
        out[(size_t)(bx + ty + i) * K + by + tx] = f2b(tile[tx][ty + i]);
}

// ---------------- gate/up interleaved transpose-cast ----------------
// packed[32q+r][k] = r<16 ? Wg[k][16q+r] : Wu[k][16q+r-16]
__global__ __launch_bounds__(256) void tcast_gu_kernel(const float* __restrict__ Wg,
                                                       const float* __restrict__ Wu,
                                                       u16* __restrict__ out,
                                                       size_t w_ls, size_t out_ls) {
    __shared__ float tg[32][17], tu[32][17];
    Wg += (size_t)blockIdx.z * w_ls;
    Wu += (size_t)blockIdx.z * w_ls;
    out += (size_t)blockIdx.z * out_ls;
    const int Q = blockIdx.x;            // 16-col gate/up group (0..175)
    const int KY = blockIdx.y * 32;      // k tile
    const int tid = threadIdx.x;
    const int tx = tid & 15, ty = tid >> 4;   // 16 cols x 16 k-rows
#pragma unroll
    for (int i = 0; i < 32; i += 16) {
        tg[ty + i][tx] = Wg[(size_t)(KY + ty + i) * FFDIM + Q * 16 + tx];
        tu[ty + i][tx] = Wu[(size_t)(KY + ty + i) * FFDIM + Q * 16 + tx];
    }
    __syncthreads();
    const int tx2 = tid & 31, ty2 = tid >> 5;   // 32 k x 8 r per pass
#pragma unroll
    for (int i = 0; i < 32; i += 8) {
        int r = ty2 + i;
        float v = (r < 16) ? tg[tx2][r] : tu[tx2][r - 16];
        out[(size_t)(Q * 32 + r) * DMODEL + KY + tx2] = f2b(v);
    }
}

// ---------------- rope cos/sin table: tbl[t*32+i] = {cos,sin}(t * theta^-i/32) ----------------
__global__ __launch_bounds__(256) void rope_table_kernel(float2* __restrict__ tbl) {
    int idx = blockIdx.x * 256 + threadIdx.x;   // < 2048*32
    int t = idx >> 5, i = idx & 31;
    float inv = expf(-(float)i * (9.210340371976184f / 32.0f));
    float ang = (float)t * inv;
    tbl[idx] = make_float2(cosf(ang), sinf(ang));
}

// ---------------- fused rope(q) + rope(k) + V-transpose (table-driven) ----------------
__global__ __launch_bounds__(256) void ropeall_kernel(const u16* __restrict__ fqkv,
                                                      const float2* __restrict__ tbl,
                                                      u16* __restrict__ qb,
                                                      u16* __restrict__ kb,
                                                      u16* __restrict__ vt) {
    __shared__ u16 tile[32][33];
    const int bid = blockIdx.x, tid = threadIdx.x;
    if (bid < 5120) {
        int i, t, hh, coloff;
        u16* out;
        size_t rest;
        if (bid < 4096) {   // q: heads=16
            int idx = bid * 256 + tid;
            i = idx & 31; rest = idx >> 5;
            t = (int)(rest >> 4); hh = (int)(rest & 15); coloff = 0; out = qb;
        } else {            // k: heads=4
            int idx = (bid - 4096) * 256 + tid;
            i = idx & 31; rest = idx >> 5;
            t = (int)(rest >> 2); hh = (int)(rest & 3); coloff = 1024; out = kb;
        }
        float2 cs = tbl[t * 32 + i];
        size_t src = (size_t)t * 1536 + coloff + hh * HEAD_DIM + 2 * i;
        size_t dst = rest * HEAD_DIM + 2 * i;
        float x0 = b2f(fqkv[src]), x1 = b2f(fqkv[src + 1]);
        out[dst]     = f2b(x0 * cs.x - x1 * cs.y);
        out[dst + 1] = f2b(x0 * cs.y + x1 * cs.x);
    } else {
        // V transpose: fqkv[:,1280:1536] -> vt[256][T]
        int b2 = bid - 5120;
        int bx = (b2 & 7) * 32;    // v-dim
        int by = (b2 >> 3) * 32;   // t
        int tx = tid & 31, ty = tid >> 5;
#pragma unroll
        for (int i = 0; i < 32; i += 8)
            tile[ty + i][tx] = fqkv[(size_t)(by + ty + i) * 1536 + 1280 + bx + tx];
        __syncthreads();
#pragma unroll
        for (int i = 0; i < 32; i += 8)
            vt[(size_t)(bx + ty + i) * T_SEQ + by + tx] = tile[tx][ty + i];
    }
}

// ---------------- GEMM-BT 128x128 (2-phase, proven): C = A * BT^T ----------------
template<bool OUT_BF16, bool ADD>
__global__ __launch_bounds__(256) void gemm_bt_kernel(const u16* __restrict__ A,
                                                      const u16* __restrict__ BT,
                                                      void* __restrict__ Cp,
                                                      int N, int K) {
    __shared__ __align__(16) u16 As[2][128 * 32];
    __shared__ __align__(16) u16 Bs[2][128 * 32];
    const int tid = threadIdx.x;
    const int gx = gridDim.x;
    const int nwg = gx * gridDim.y;
    const int hwid = blockIdx.y * gx + blockIdx.x;
    const int q = nwg >> 3, r = nwg & 7;
    const int xcd = hwid & 7, rem = hwid >> 3;
    const int wgid = (xcd < r ? xcd * (q + 1) : r * (q + 1) + (xcd - r) * q) + rem;
    const int brow = wgid % gx, bcol = wgid / gx;

    const int w = tid >> 6, lane = tid & 63;
    const int wr = w >> 1, wc = w & 1;
    const int lg = lane >> 4, lr = lane & 15;

    f32x4 acc[4][4] = {};

    const int srow = w * 32 + (lane >> 2);
    const int scol = (lane & 3) << 3;
    const u16* gA = A + (size_t)(brow * 128 + srow) * K + scol;
    const u16* gB = BT + (size_t)(bcol * 128 + srow) * K + scol;
    const size_t koff16 = (size_t)16 * K;
    const int lofs0 = (w * 32) * 32;
    const int lofs1 = (w * 32 + 16) * 32;

    const int nt = K >> 5;
    gload16(gA, &As[0][lofs0]);
    gload16(gA + koff16, &As[0][lofs1]);
    gload16(gB, &Bs[0][lofs0]);
    gload16(gB + koff16, &Bs[0][lofs1]);
    __syncthreads();

    int cur = 0;
    for (int t = 0; t < nt; t++) {
        if (t + 1 < nt) {
            const int kb = (t + 1) << 5;
            gload16(gA + kb, &As[cur ^ 1][lofs0]);
            gload16(gA + koff16 + kb, &As[cur ^ 1][lofs1]);
            gload16(gB + kb, &Bs[cur ^ 1][lofs0]);
            gload16(gB + koff16 + kb, &Bs[cur ^ 1][lofs1]);
        }
        bf16x8 aF[4], bF[4];
#pragma unroll
        for (int m = 0; m < 4; m++)
            aF[m] = *(const bf16x8*)(&As[cur][(wr * 64 + m * 16 + lr) * 32 + lg * 8]);
#pragma unroll
        for (int n = 0; n < 4; n++)
            bF[n] = *(const bf16x8*)(&Bs[cur][(wc * 64 + n * 16 + lr) * 32 + lg * 8]);
#pragma unroll
        for (int m = 0; m < 4; m++)
#pragma unroll
            for (int n = 0; n < 4; n++)
                acc[m][n] = __builtin_amdgcn_mfma_f32_16x16x32_bf16(aF[m], bF[n], acc[m][n], 0, 0, 0);
        __syncthreads();
        cur ^= 1;
    }

#pragma unroll
    for (int m = 0; m < 4; m++)
#pragma unroll
        for (int n = 0; n < 4; n++)
#pragma unroll
            for (int j = 0; j < 4; j++) {
                int row = brow * 128 + wr * 64 + m * 16 + lg * 4 + j;
                int col = bcol * 128 + wc * 64 + n * 16 + lr;
                size_t idx = (size_t)row * N + col;
                float v = acc[m][n][j];
                if constexpr (OUT_BF16) {
                    ((u16*)Cp)[idx] = f2b(v);
                } else if constexpr (ADD) {
                    ((float*)Cp)[idx] = ((const float*)Cp)[idx] + v;
                } else {
                    ((float*)Cp)[idx] = v;
                }
            }
}

// ---------------- GEMM-BT 256x256, 4-buffer deep-pipelined ----------------
// r13/r14 verified structure, depth 3->4: stage tile t+3 during tile t
// (A @phase0, B @phase1). LDS 128KB: A[4buf][16KB] @0, B same @64KB.
// WAR: buf (t+3)%4 last ds_read in tile t-1 (t-1 == t+3 mod 4), complete
// before t-1's end barrier; stages issue >=1 barrier later. RAW: at end of
// tile t outstanding <= {t+1,t+2,t+3}x4 -> vmcnt(8) ensures t+1 landed;
// tail vmcnt(4)/vmcnt(0). Prefetch now spans ~4 phases (covers HBM miss).
// MODE 0: f32 C. MODE 3: fused silu-pair (gate/up interleaved BT) -> bf16.
template<int MODE>
__global__ __launch_bounds__(512) void gemm256_kernel(const u16* __restrict__ A,
                                                      const u16* __restrict__ BT,
                                                      void* __restrict__ Cp,
                                                      int Nout, int K) {
    extern __shared__ __align__(16) u16 lds[];
    const int tid = threadIdx.x;
    const int gx = gridDim.x;
    const int nwg = gx * gridDim.y;
    const int hwid = blockIdx.y * gx + blockIdx.x;
    const int q = nwg >> 3, r = nwg & 7;
    const int xcd = hwid & 7, rem = hwid >> 3;
    const int wgid = (xcd < r ? xcd * (q + 1) : r * (q + 1) + (xcd - r) * q) + rem;
    const int bR = wgid % gx, bC = wgid / gx;

    const int w = tid >> 6, lane = tid & 63;
    const int wm = w >> 2, wn = w & 3;
    const int lg = lane >> 4, lr = lane & 15;

    f32x4 acc[8][4] = {};

    const int srow = lane >> 2;                                    // row in band
    const int scol = ((lane & 3) ^ ((lane >= 32) ? 2 : 0)) << 3;   // swizzled src col
    const int rblk = (((lr >= 8) ? (lg ^ 2) : lg)) << 4;           // ds_read byte blk

    const u16* Ab = A + (size_t)(bR * 256) * K + scol;
    const u16* Bb = BT + (size_t)(bC * 256) * K + scol;

    auto STAGE_A = [&](int t, int b) {
        gload16(Ab + (size_t)(w * 16 + srow) * K + t * 32,
                lds + (b * 16384 + w * 1024) / 2);
        gload16(Ab + (size_t)((w + 8) * 16 + srow) * K + t * 32,
                lds + (b * 16384 + (w + 8) * 1024) / 2);
    };
    auto STAGE_B = [&](int t, int b) {
        gload16(Bb + (size_t)(w * 16 + srow) * K + t * 32,
                lds + (65536 + b * 16384 + w * 1024) / 2);
        gload16(Bb + (size_t)((w + 8) * 16 + srow) * K + t * 32,
                lds + (65536 + b * 16384 + (w + 8) * 1024) / 2);
    };

    const int nt = K >> 5;
    // prologue: tiles 0,1,2 -> bufs 0,1,2; wait tile 0 (tiles 1,2 = 8 in flight)
    STAGE_A(0, 0); STAGE_B(0, 0);
    STAGE_A(1, 1); STAGE_B(1, 1);
    STAGE_A(2, 2); STAGE_B(2, 2);
    asm volatile("s_waitcnt vmcnt(8)" ::: "memory");
    __builtin_amdgcn_s_barrier();

    int cur = 0;
    for (int t = 0; t < nt; t++) {
        const bool st = (t + 3 < nt);
        const int nb = (cur + 3) & 3;
        bf16x8 bF[4];
        // ---- phase 0: m-frags 0-3 (reads bF for the whole tile) ----
        {
            bf16x8 aF[4];
#pragma unroll
            for (int mi = 0; mi < 4; mi++)
                aF[mi] = *(const bf16x8*)((const char*)lds + cur * 16384 +
                                          (wm * 8 + mi) * 1024 + lr * 64 + rblk);
#pragma unroll
            for (int n = 0; n < 4; n++)
                bF[n] = *(const bf16x8*)((const char*)lds + 65536 + cur * 16384 +
                                         (wn * 4 + n) * 1024 + lr * 64 + rblk);
            if (st) STAGE_A(t + 3, nb);
            __builtin_amdgcn_s_barrier();
            asm volatile("s_waitcnt lgkmcnt(0)" ::: "memory");
            __builtin_amdgcn_sched_barrier(0);
            __builtin_amdgcn_s_setprio(1);
#pragma unroll
            for (int mi = 0; mi < 4; mi++)
#pragma unroll
                for (int n = 0; n < 4; n++)
                    acc[mi][n] = __builtin_amdgcn_mfma_f32_16x16x32_bf16(
                        aF[mi], bF[n], acc[mi][n], 0, 0, 0);
            __builtin_amdgcn_s_setprio(0);
            __builtin_amdgcn_s_barrier();
        }
        // ---- phase 1: m-frags 4-7 (reuses bF registers) ----
        {
            bf16x8 aF[4];
#pragma unroll
            for (int mi = 0; mi < 4; mi++)
                aF[mi] = *(const bf16x8*)((const char*)lds + cur * 16384 +
                                          (wm * 8 + 4 + mi) * 1024 + lr * 64 + rblk);
            if (st) STAGE_B(t + 3, nb);
            if (t + 1 < nt) {
                if (st)               asm volatile("s_waitcnt vmcnt(8)" ::: "memory");
                else if (t + 2 < nt)  asm volatile("s_waitcnt vmcnt(4)" ::: "memory");
                else                  asm volatile("s_waitcnt vmcnt(0)" ::: "memory");
            }
            __builtin_amdgcn_s_barrier();
            asm volatile("s_waitcnt lgkmcnt(0)" ::: "memory");
            __builtin_amdgcn_sched_barrier(0);
            __builtin_amdgcn_s_setprio(1);
#pragma unroll
            for (int mi = 0; mi < 4; mi++)
#pragma unroll
                for (int n = 0; n < 4; n++)
                    acc[4 + mi][n] = __builtin_amdgcn_mfma_f32_16x16x32_bf16(
                        aF[mi], bF[n], acc[4 + mi][n], 0, 0, 0);
            __builtin_amdgcn_s_setprio(0);
            __builtin_amdgcn_s_barrier();
        }
        cur = (cur + 1) & 3;
    }

#pragma unroll
    for (int m = 0; m < 8; m++) {
        if constexpr (MODE == 0) {
#pragma unroll
            for (int n = 0; n < 4; n++)
#pragma unroll
                for (int jj = 0; jj < 4; jj++) {
                    int row = bR * 256 + wm * 128 + m * 16 + lg * 4 + jj;
                    int col = bC * 256 + wn * 64 + n * 16 + lr;
                    ((float*)Cp)[(size_t)row * Nout + col] = acc[m][n][jj];
                }
        } else {
#pragma unroll
            for (int n = 0; n < 4; n += 2)
#pragma unroll
                for (int jj = 0; jj < 4; jj++) {
                    int row = bR * 256 + wm * 128 + m * 16 + lg * 4 + jj;
                    int col = bC * 128 + wn * 32 + (n >> 1) * 16 + lr;
                    float g = acc[m][n][jj], u = acc[m][n + 1][jj];
                    float s = g / (1.f + __expf(-g));
                    ((u16*)Cp)[(size_t)row * Nout + col] = f2b(s * u);
                }
        }
    }
}

// ---------------- fallback GEMM (f32 B, non-transposed) — LM head only ----------------
__device__ __forceinline__ int bs_off(int c, int k) {
    return c * 40 + ((((k >> 3) ^ ((c >> 3) & 3)) << 3) | (k & 7));
}

__global__ __launch_bounds__(256) void gemm_f32b_kernel(const u16* __restrict__ A,
                                                        const float* __restrict__ B,
                                                        float* __restrict__ C,
                                                        int N, int K) {
    __shared__ __align__(16) u16 As[128 * 40];
    __shared__ __align__(16) u16 Bs[128 * 40];
    const int tid = threadIdx.x;
    const int brow = blockIdx.y, bcol = blockIdx.x;
    const int wid = tid >> 6, lane = tid & 63;
    const int wr = wid >> 1, wc = wid & 1;
    const int lg = lane >> 4, lr = lane & 15;

    f32x4 acc[4][4] = {};
    const int ar = tid >> 2, ac = (tid & 3) << 3;
    const int bk = tid >> 4, bc = (tid & 15) << 3;

    for (int kb = 0; kb < K; kb += 32) {
        {
            const u16* ga = A + (size_t)(brow * 128 + ar) * K + kb + ac;
            *(uint4*)(&As[ar * 40 + ac]) = *(const uint4*)ga;
            *(uint4*)(&As[(ar + 64) * 40 + ac]) = *(const uint4*)(ga + (size_t)64 * K);
        }
        {
            const float* gb = B + (size_t)(kb + bk) * N + bcol * 128 + bc;
            float4 a0 = *(const float4*)gb;
            float4 a1 = *(const float4*)(gb + 4);
            float4 b0 = *(const float4*)(gb + (size_t)16 * N);
            float4 b1 = *(const float4*)(gb + (size_t)16 * N + 4);
            float f0[8] = {a0.x, a0.y, a0.z, a0.w, a1.x, a1.y, a1.z, a1.w};
            float f1[8] = {b0.x, b0.y, b0.z, b0.w, b1.x, b1.y, b1.z, b1.w};
#pragma unroll
            for (int i = 0; i < 8; i++) {
                Bs[bs_off(bc + i, bk)] = f2b(f0[i]);
                Bs[bs_off(bc + i, bk + 16)] = f2b(f1[i]);
            }
        }
        __syncthreads();

        bf16x8 aF[4], bF[4];
#pragma unroll
        for (int m = 0; m < 4; m++)
            aF[m] = *(const bf16x8*)(&As[(wr * 64 + m * 16 + lr) * 40 + lg * 8]);
#pragma unroll
        for (int n = 0; n < 4; n++) {
            int c = wc * 64 + n * 16 + lr;
            bF[n] = *(const bf16x8*)(&Bs[c * 40 + ((lg ^ ((c >> 3) & 3)) << 3)]);
        }
#pragma unroll
        for (int m = 0; m < 4; m++)
#pragma unroll
            for (int n = 0; n < 4; n++)
                acc[m][n] = __builtin_amdgcn_mfma_f32_16x16x32_bf16(aF[m], bF[n], acc[m][n], 0, 0, 0);
        __syncthreads();
    }

#pragma unroll
    for (int m = 0; m < 4; m++)
#pragma unroll
        for (int n = 0; n < 4; n++)
#pragma unroll
            for (int j = 0; j < 4; j++) {
                int row = brow * 128 + wr * 64 + m * 16 + lg * 4 + j;
                int col = bcol * 128 + wc * 64 + n * 16 + lr;
                C[(size_t)row * N + col] = acc[m][n][j];
            }
}

// ---------------- flash attention: 128 q-rows x 1 head, 8 waves ----------------
__global__ __launch_bounds__(512) void fattn_kernel(const u16* __restrict__ q,
                                                    const u16* __restrict__ k,
                                                    const u16* __restrict__ vt,
                                                    u16* __restrict__ out) {
    extern __shared__ __align__(16) u16 smem[];
    u16* Ks = smem;                          // KBLK*KSS   = 9216 u16
    u16* Vt = smem + KBLK * KSS;             // HEAD_DIM*VTS = 8704 u16
    u16* Ps = Vt + HEAD_DIM * VTS;           // QBLK*PSS   = 17408 u16
    const int tid = threadIdx.x;
    const int qb0 = blockIdx.x * QBLK, h = blockIdx.y, kvh = h >> 2;
    const int w = tid >> 6, lane = tid & 63;
    const int lg = lane >> 4, lr = lane & 15;

    bf16x8 qf0, qf1;
    {
        const u16* src = q + ((size_t)(qb0 + w * 16 + lr) * NH + h) * HEAD_DIM;
        qf0 = *(const bf16x8*)(src + lg * 8);
        qf1 = *(const bf16x8*)(src + 32 + lg * 8);
    }

    f32x4 acc_o[4] = {};
    float m_run[4] = {-1e30f, -1e30f, -1e30f, -1e30f};
    float l_run[4] = {0.f, 0.f, 0.f, 0.f};

    const int ntiles = blockIdx.x + 1;   // QBLK == KBLK

    for (int kt = 0; kt < ntiles; kt++) {
        const int kb = kt * KBLK;
        __syncthreads();
        for (int c = tid; c < KBLK * 8; c += 512) {
            int row = c >> 3, c8 = (c & 7) << 3;
            *(uint4*)(&Ks[row * KSS + c8]) =
                *(const uint4*)(k + ((size_t)(kb + row) * NKV + kvh) * HEAD_DIM + c8);
        }
        for (int c = tid; c < HEAD_DIM * 16; c += 512) {
            int d = c >> 4, c16 = (c & 15) << 3;
            *(uint4*)(&Vt[d * VTS + c16]) =
                *(const uint4*)(vt + (size_t)(kvh * HEAD_DIM + d) * T_SEQ + kb + c16);
        }
        __syncthreads();

        f32x4 s[8] = {};
#pragma unroll
        for (int n = 0; n < 8; n++) {
            bf16x8 kf0 = *(const bf16x8*)(&Ks[(n * 16 + lr) * KSS + lg * 8]);
            bf16x8 kf1 = *(const bf16x8*)(&Ks[(n * 16 + lr) * KSS + 32 + lg * 8]);
            s[n] = __builtin_amdgcn_mfma_f32_16x16x32_bf16(qf0, kf0, s[n], 0, 0, 0);
            s[n] = __builtin_amdgcn_mfma_f32_16x16x32_bf16(qf1, kf1, s[n], 0, 0, 0);
        }

#pragma unroll
        for (int j = 0; j < 4; j++) {
            int q_g = qb0 + w * 16 + lg * 4 + j;
            float sv[8];
            float tmax = -1e30f;
#pragma unroll
            for (int n = 0; n < 8; n++) {
                float xx = s[n][j] * 0.125f;
                if (kb + n * 16 + lr > q_g) xx = -1e30f;
                sv[n] = xx;
                tmax = fmaxf(tmax, xx);
            }
#pragma unroll
            for (int mm = 1; mm < 16; mm <<= 1) tmax = fmaxf(tmax, __shfl_xor(tmax, mm));
            float mn = fmaxf(m_run[j], tmax);
            float sc = __expf(m_run[j] - mn);
            m_run[j] = mn;
            float rsum = 0.f;
#pragma unroll
            for (int n = 0; n < 8; n++) {
                float p = __expf(sv[n] - mn);
                rsum += p;
                Ps[(w * 16 + lg * 4 + j) * PSS + n * 16 + lr] = f2b(p);
            }
#pragma unroll
            for (int mm = 1; mm < 16; mm <<= 1) rsum += __shfl_xor(rsum, mm);
            l_run[j] = l_run[j] * sc + rsum;
#pragma unroll
            for (int n = 0; n < 4; n++) acc_o[n][j] *= sc;
        }

#pragma unroll
        for (int ks = 0; ks < 4; ks++) {
            bf16x8 pf = *(const bf16x8*)(&Ps[(w * 16 + lr) * PSS + ks * 32 + lg * 8]);
#pragma unroll
            for (int n = 0; n < 4; n++) {
                bf16x8 vf = *(const bf16x8*)(&Vt[(n * 16 + lr) * VTS + ks * 32 + lg * 8]);
                acc_o[n] = __builtin_amdgcn_mfma_f32_16x16x32_bf16(pf, vf, acc_o[n], 0, 0, 0);
            }
        }
    }

#pragma unroll
    for (int n = 0; n < 4; n++)
#pragma unroll
        for (int j = 0; j < 4; j++) {
            int t = qb0 + w * 16 + lg * 4 + j;
            int d = n * 16 + lr;
            out[((size_t)t * NH + h) * HEAD_DIM + d] = f2b(acc_o[n][j] / l_run[j]);
        }
}

// ---------------- host launch ----------------
extern "C" void kernel_launch(void* const* d_in, const int* in_sizes, int n_in,
                              void* d_out, int out_size, void* d_ws, size_t ws_size,
                              hipStream_t stream) {
    const int*   toks = (const int*)d_in[0];
    const float* emb  = (const float*)d_in[1];
    const float* Wq   = (const float*)d_in[2];
    const float* Wk   = (const float*)d_in[3];
    const float* Wv   = (const float*)d_in[4];
    const float* Wo   = (const float*)d_in[5];
    const float* Wg   = (const float*)d_in[6];
    const float* Wu   = (const float*)d_in[7];
    const float* Wd   = (const float*)d_in[8];
    const float* ln1  = (const float*)d_in[9];
    const float* ln2  = (const float*)d_in[10];
    const float* nw   = (const float*)d_in[11];
    const float* Wlm  = (const float*)d_in[12];

    // ---- scratch layout in d_out (262MB, all dead before LM head writes) ----
    char* ob = (char*)d_out;
    const size_t MB = 1024 * 1024;
    float* x    = (float*)(ob + 0 * MB);    // 8MB   residual [T,D] f32
    u16* fqkv   = (u16*)  (ob + 8 * MB);    // 6MB   [T,1536] qkv packed bf16
    float2* tbl = (float2*)(ob + 16 * MB);  // 512KB rope table
    u16* vt     = (u16*)  (ob + 40 * MB);   // 1MB   V^T [256][T]
    u16* qb     = (u16*)  (ob + 42 * MB);   // 4MB
    u16* kb     = (u16*)  (ob + 47 * MB);   // 1MB
    u16* attnb  = (u16*)  (ob + 48 * MB);   // 4MB
    u16* ffb    = (u16*)  (ob + 52 * MB);   // 11.5MB
    // packed bf16 transposed weights at 64MB+: per-layer region, fixed offsets
    u16* Wt = (u16*)(ob + 64 * MB);
    const size_t OFF_QKV = 0;
    const size_t OFF_O   = (size_t)1536 * 1024;
    const size_t OFF_GU  = OFF_O + (size_t)1024 * 1024;      // gate/up interleaved [5632][1024]
    const size_t OFF_D   = OFF_GU + (size_t)5632 * 1024;
    const size_t LS      = OFF_D + (size_t)2816 * 1024;      // elems/layer
    u16* h = (u16*)d_ws;   // 4MB bf16 [T,D]
    bool ws_big = ws_size >= 72 * MB;
    u16* WlmT = ws_big ? (u16*)((char*)d_ws + 4 * MB) : nullptr;  // [NVOCAB][DMODEL]
    (void)in_sizes; (void)n_in; (void)out_size;

    dim3 blk(256);
    auto tc = [&](const float* in, u16* out, int K, int N, size_t in_ls, int nz) {
        tcast_kernel<<<dim3(N / 32, K / 32, nz), blk, 0, stream>>>(in, out, K, N, in_ls, LS);
    };
    auto gemm_f32 = [&](const u16* A, const u16* BT, float* C, int N, int K, bool add) {
        dim3 g(T_SEQ / 128, N / 128);
        if (add) gemm_bt_kernel<false, true><<<g, blk, 0, stream>>>(A, BT, (void*)C, N, K);
        else     gemm_bt_kernel<false, false><<<g, blk, 0, stream>>>(A, BT, (void*)C, N, K);
    };
    auto gemm_b16 = [&](const u16* A, const u16* BT, u16* C, int N, int K) {
        dim3 g(T_SEQ / 128, N / 128);
        gemm_bt_kernel<true, false><<<g, blk, 0, stream>>>(A, BT, (void*)C, N, K);
    };

    // ---- one-time weight transpose-casts ----
    tc(Wq, Wt + OFF_QKV,                       DMODEL, NH * HEAD_DIM,  (size_t)DMODEL * NH * HEAD_DIM, 2);
    tc(Wk, Wt + OFF_QKV + (size_t)1024 * 1024, DMODEL, NKV * HEAD_DIM, (size_t)DMODEL * NKV * HEAD_DIM, 2);
    tc(Wv, Wt + OFF_QKV + (size_t)1280 * 1024, DMODEL, NKV * HEAD_DIM, (size_t)DMODEL * NKV * HEAD_DIM, 2);
    tc(Wo, Wt + OFF_O,                         DMODEL, DMODEL,         (size_t)DMODEL * DMODEL, 2);
    tcast_gu_kernel<<<dim3(FFDIM / 16, DMODEL / 32, 2), blk, 0, stream>>>(
        Wg, Wu, Wt + OFF_GU, (size_t)DMODEL * FFDIM, LS);
    tc(Wd, Wt + OFF_D,                         FFDIM,  DMODEL,         (size_t)FFDIM * DMODEL, 2);
    if (WlmT)
        tcast_kernel<<<dim3(NVOCAB / 32, DMODEL / 32, 1), blk, 0, stream>>>(
            Wlm, WlmT, DMODEL, NVOCAB, 0, 0);
    rope_table_kernel<<<dim3(T_SEQ * 32 / 256), blk, 0, stream>>>(tbl);

    // dynamic-LDS attributes
    (void)hipFuncSetAttribute(reinterpret_cast<const void*>(gemm256_kernel<0>),
                              hipFuncAttributeMaxDynamicSharedMemorySize, 131072);
    (void)hipFuncSetAttribute(reinterpret_cast<const void*>(gemm256_kernel<3>),
                              hipFuncAttributeMaxDynamicSharedMemorySize, 131072);
    const int FATTN_LDS = (KBLK * KSS + HEAD_DIM * VTS + QBLK * PSS) * 2;   // 70656
    (void)hipFuncSetAttribute(reinterpret_cast<const void*>(fattn_kernel),
                              hipFuncAttributeMaxDynamicSharedMemorySize, FATTN_LDS);

    // embed + layer-0 rmsnorm fused
    embed_rms_kernel<<<dim3(T_SEQ), blk, 0, stream>>>(toks, emb, ln1, x, h);

    for (int l = 0; l < 2; l++) {
        const u16* WqkvT = Wt + (size_t)l * LS + OFF_QKV;
        const u16* WoT   = Wt + (size_t)l * LS + OFF_O;
        const u16* WguT  = Wt + (size_t)l * LS + OFF_GU;
        const u16* WdT   = Wt + (size_t)l * LS + OFF_D;

        // attn block (h already holds rmsnorm(x, ln1[l]))
        if (l > 0)
            rmsnorm_kernel<<<dim3(T_SEQ), blk, 0, stream>>>(x, ln1 + (size_t)l * DMODEL, h);
        gemm_b16(h, WqkvT, fqkv, 1536, DMODEL);
        ropeall_kernel<<<dim3(5632), blk, 0, stream>>>(fqkv, tbl, qb, kb, vt);
        fattn_kernel<<<dim3(T_SEQ / QBLK, NH), dim3(512), FATTN_LDS, stream>>>(qb, kb, vt, attnb);
        gemm_f32(attnb, WoT, x, DMODEL, DMODEL, true);   // fused residual add

        // ffn block: GU gemm256 with fused silu -> ffb (bf16), then down-proj
        rmsnorm_kernel<<<dim3(T_SEQ), blk, 0, stream>>>(x, ln2 + (size_t)l * DMODEL, h);
        {
            dim3 g(T_SEQ / 256, 5632 / 256);   // 8 x 22 = 176 blocks, %8 == 0
            gemm256_kernel<3><<<g, dim3(512), 131072, stream>>>(h, WguT, (void*)ffb,
                                                                FFDIM, DMODEL);
        }
        gemm_f32(ffb, WdT, x, DMODEL, FFDIM, true);      // fused residual add
    }

    // final norm + lm head
    rmsnorm_kernel<<<dim3(T_SEQ), blk, 0, stream>>>(x, nw, h);
    if (WlmT) {
        dim3 g(T_SEQ / 256, NVOCAB / 256);
        gemm256_kernel<0><<<g, dim3(512), 131072, stream>>>(h, WlmT, (void*)d_out,
                                                            NVOCAB, DMODEL);
    } else {
        dim3 g(NVOCAB / 128, T_SEQ / 128);
        gemm_f32b_kernel<<<g, blk, 0, stream>>>(h, Wlm, (float*)d_out, NVOCAB, DMODEL);
    }
}